// Round 2
// baseline (2600.042 us; speedup 1.0000x reference)
//
#include <hip/hip_runtime.h>

// SGNet on MI355X. fp32 inputs/outputs (per reference dtype), internal bf16
// MFMA pipeline with fp32 master copies for GRU hidden states.
//  - Weights fp32 -> transposed [N,K] bf16 once per call (gemm_bt pattern,
//    mfma_f32_16x16x32_bf16, verified C/D layout col=lane&15,row=(lane>>4)*4+r).
//  - Goal GRU (12 steps) fused into one kernel (per-batch-row recurrence).
//  - All 8 decoders batched into one M=4096 decoder (decoder is a pure sink).

typedef unsigned short u16;
typedef __attribute__((ext_vector_type(8))) short bf16x8;
typedef __attribute__((ext_vector_type(4))) float f32x4;

static __device__ __forceinline__ float b2f(u16 u) {
  union { float f; unsigned int i; } x; x.i = ((unsigned int)u) << 16; return x.f;
}
static __device__ __forceinline__ u16 f2b(float f) {
  unsigned int u = __float_as_uint(f);
  unsigned int r = (u + 0x7FFFu + ((u >> 16) & 1u)) >> 16;
  return (u16)r;
}

// ---------------------------------------------------------------- transpose + cvt
// in fp32 [K,N] row-major -> out bf16 [N,K] row-major. K,N multiples of 32.
__global__ __launch_bounds__(256) void transpose_f2b(const float* __restrict__ in,
                                                     u16* __restrict__ out,
                                                     int K, int N) {
  __shared__ u16 t[32][33];
  int n0 = blockIdx.x * 32, k0 = blockIdx.y * 32;
  int x = threadIdx.x & 31, y = threadIdx.x >> 5;  // 32 x 8
  for (int i = 0; i < 4; i++) t[y + 8 * i][x] = f2b(in[(size_t)(k0 + y + 8 * i) * N + n0 + x]);
  __syncthreads();
  for (int i = 0; i < 4; i++) out[(size_t)(n0 + y + 8 * i) * K + k0 + x] = t[x][y + 8 * i];
}

// ---------------------------------------------------------------- embed
// traj[e][b][h] = relu(sum_i inputs[b][e][i] * W[i][h] + bias[h]), K=6
__global__ __launch_bounds__(256) void embed_kernel(const float* __restrict__ inp,
                                                    const float* __restrict__ w,
                                                    const float* __restrict__ bias,
                                                    u16* __restrict__ traj) {
  int t = blockIdx.x * 256 + threadIdx.x;             // 8*512*512
  int h = t & 511, b = (t >> 9) & 511, e = t >> 18;
  float acc = bias[h];
  for (int i = 0; i < 6; i++) acc += inp[(b * 8 + e) * 6 + i] * w[i * 512 + h];
  traj[((e * 512) + b) * 512 + h] = f2b(fmaxf(acc, 0.f));
}

// ---------------------------------------------------------------- copy x_t -> xcat[:,0:512]
__global__ __launch_bounds__(256) void copy_xt(const u16* __restrict__ traj_e,
                                               u16* __restrict__ xcat) {
  int t = blockIdx.x * 256 + threadIdx.x;   // 512*512/8 = 32768
  int r = t >> 6, c8 = (t & 63) * 8;
  *(uint4*)&xcat[r * 640 + c8] = *(const uint4*)&traj_e[r * 512 + c8];
}

// ---------------------------------------------------------------- generic MFMA GEMM (B^T)
// C[M,N] = act(A[M,K] @ W^T + bias); A [M,K] bf16, W [N,K] bf16 (pre-transposed).
// M,N multiples of 64; K multiple of 64. Optional dual fp32 output.
__global__ __launch_bounds__(256) void gemm_bt(const u16* __restrict__ A, int lda,
                                               const u16* __restrict__ W, int ldw,
                                               const float* __restrict__ bias,
                                               u16* __restrict__ Cb, int ldc,
                                               float* __restrict__ Cf,
                                               int K, int relu) {
  __shared__ u16 As[64][72];  // +8 bf16 pad: breaks 32-bank row aliasing
  __shared__ u16 Bs[64][72];
  int tid = threadIdx.x;
  int m0 = blockIdx.y * 64, n0 = blockIdx.x * 64;
  int lane = tid & 63, wave = tid >> 6;
  int wr = wave >> 1, wc = wave & 1;
  int mrow = lane & 15, kq = (lane >> 4) * 8;
  f32x4 acc[2][2] = {};

  for (int k0 = 0; k0 < K; k0 += 64) {
    __syncthreads();
    for (int c = tid; c < 512; c += 256) {
      int r = c >> 3, kk = (c & 7) * 8;
      *(uint4*)&As[r][kk] = *(const uint4*)&A[(size_t)(m0 + r) * lda + k0 + kk];
      *(uint4*)&Bs[r][kk] = *(const uint4*)&W[(size_t)(n0 + r) * ldw + k0 + kk];
    }
    __syncthreads();
    for (int ks = 0; ks < 2; ks++) {
      bf16x8 af[2], bf[2];
      for (int i = 0; i < 2; i++) {
        af[i] = *(const bf16x8*)&As[wr * 32 + i * 16 + mrow][ks * 32 + kq];
        bf[i] = *(const bf16x8*)&Bs[wc * 32 + i * 16 + mrow][ks * 32 + kq];
      }
      for (int i = 0; i < 2; i++)
        for (int j = 0; j < 2; j++)
          acc[i][j] = __builtin_amdgcn_mfma_f32_16x16x32_bf16(af[i], bf[j], acc[i][j], 0, 0, 0);
    }
  }
  int col = lane & 15, rq = (lane >> 4) * 4;
  for (int i = 0; i < 2; i++)
    for (int j = 0; j < 2; j++) {
      int n = n0 + wc * 32 + j * 16 + col;
      float bv = bias ? bias[n] : 0.f;
      for (int r = 0; r < 4; r++) {
        int m = m0 + wr * 32 + i * 16 + rq + r;
        float v = acc[i][j][r] + bv;
        if (relu) v = fmaxf(v, 0.f);
        Cb[(size_t)m * ldc + n] = f2b(v);
        if (Cf) Cf[(size_t)m * ldc + n] = v;
      }
    }
}

// ---------------------------------------------------------------- GRU pointwise (H=512)
// gates [rows,1536] bf16 (bias already added), hf fp32 master, hb bf16 copy.
__global__ __launch_bounds__(256) void gru_pw(const u16* __restrict__ gi,
                                              const u16* __restrict__ gh,
                                              float* __restrict__ hf,
                                              u16* __restrict__ hb, int rows) {
  int t = blockIdx.x * 256 + threadIdx.x;
  if (t >= rows * 512) return;
  int j = t & 511, r = t >> 9;
  size_t base = (size_t)r * 1536;
  float ir = b2f(gi[base + j]),        iz = b2f(gi[base + 512 + j]),  inn = b2f(gi[base + 1024 + j]);
  float hr = b2f(gh[base + j]),        hz = b2f(gh[base + 512 + j]),  hn  = b2f(gh[base + 1024 + j]);
  float rr = 1.f / (1.f + expf(-(ir + hr)));
  float zz = 1.f / (1.f + expf(-(iz + hz)));
  float nn = tanhf(inn + rr * hn);
  float h = hf[t];
  float ho = (1.f - zz) * nn + zz * h;
  hf[t] = ho;
  hb[t] = f2b(ho);
}

// ---------------------------------------------------------------- fused goal-GRU loop
// 12 steps, per-row recurrence. Block owns 16 batch rows; fp32 state in LDS.
__global__ __launch_bounds__(256) void goal_fused(const u16* __restrict__ gh0,      // [512,128] bf16
                                                  const u16* __restrict__ wih_t,    // [384,128] bf16
                                                  const u16* __restrict__ whh_t,    // [384,128] bf16
                                                  const float* __restrict__ bih,    // [384]
                                                  const float* __restrict__ bhh,    // [384]
                                                  const u16* __restrict__ g2i_t,    // [128,128] bf16
                                                  const float* __restrict__ g2i_b,  // [128]
                                                  u16* __restrict__ goals) {        // [12,512,128] bf16
  __shared__ float ghf[16][128];
  __shared__ u16   ghb[16][128];
  __shared__ u16   gib[16][128];
  __shared__ float gi3[16][384];
  __shared__ float gh3[16][384];
  int tid = threadIdx.x;
  int r0 = blockIdx.x * 16;
  int lane = tid & 63, wave = tid >> 6;
  int mrow = lane & 15, kq = (lane >> 4) * 8;

  for (int idx = tid; idx < 16 * 128; idx += 256) {
    int m = idx >> 7, j = idx & 127;
    u16 u = gh0[(r0 + m) * 128 + j];
    ghb[m][j] = u; ghf[m][j] = b2f(u); gib[m][j] = 0;
  }
  __syncthreads();

  for (int t = 0; t < 12; t++) {
    // phase 1: gi3 = gi @ wih + bih ; gh3 = gh @ whh + bhh   (M=16, N=384, K=128)
    for (int tt = wave; tt < 48; tt += 4) {
      bool isI = tt < 24;
      int n0 = (isI ? tt : tt - 24) * 16;
      const u16* Wt = isI ? wih_t : whh_t;
      const float* Bv = isI ? bih : bhh;
      const u16(*Ab)[128] = isI ? gib : ghb;
      f32x4 acc = {};
      for (int ks = 0; ks < 4; ks++) {
        bf16x8 a = *(const bf16x8*)&Ab[mrow][ks * 32 + kq];
        bf16x8 b = *(const bf16x8*)&Wt[(n0 + mrow) * 128 + ks * 32 + kq];
        acc = __builtin_amdgcn_mfma_f32_16x16x32_bf16(a, b, acc, 0, 0, 0);
      }
      int n = n0 + (lane & 15);
      float bv = Bv[n];
      float* G = isI ? &gi3[0][0] : &gh3[0][0];
      for (int r = 0; r < 4; r++) {
        int m = (lane >> 4) * 4 + r;
        G[m * 384 + n] = acc[r] + bv;
      }
    }
    __syncthreads();
    // phase 2: pointwise GRU update + emit goals[t]
    for (int idx = tid; idx < 16 * 128; idx += 256) {
      int m = idx >> 7, j = idx & 127;
      float rr = 1.f / (1.f + expf(-(gi3[m][j] + gh3[m][j])));
      float zz = 1.f / (1.f + expf(-(gi3[m][128 + j] + gh3[m][128 + j])));
      float nn = tanhf(gi3[m][256 + j] + rr * gh3[m][256 + j]);
      float h = ghf[m][j];
      float ho = (1.f - zz) * nn + zz * h;
      ghf[m][j] = ho;
      u16 hb = f2b(ho);
      ghb[m][j] = hb;
      goals[(t * 512 + r0 + m) * 128 + j] = hb;
    }
    __syncthreads();
    // phase 3: gi = relu(gh_new @ gh2i + b)   (M=16, N=128, K=128)
    for (int tt = wave; tt < 8; tt += 4) {
      int n0 = tt * 16;
      f32x4 acc = {};
      for (int ks = 0; ks < 4; ks++) {
        bf16x8 a = *(const bf16x8*)&ghb[mrow][ks * 32 + kq];
        bf16x8 b = *(const bf16x8*)&g2i_t[(n0 + mrow) * 128 + ks * 32 + kq];
        acc = __builtin_amdgcn_mfma_f32_16x16x32_bf16(a, b, acc, 0, 0, 0);
      }
      int n = n0 + (lane & 15);
      float bv = g2i_b[n];
      for (int r = 0; r < 4; r++) {
        int m = (lane >> 4) * 4 + r;
        gib[m][n] = f2b(fmaxf(acc[r] + bv, 0.f));
      }
    }
    __syncthreads();
  }
}

// ---------------------------------------------------------------- reg head (wave per row)
// out[((b*8+e)*12+td)*2 + {0,1}] = X[row,:512] @ reg_w + reg_b  (fp32 out)
__global__ __launch_bounds__(256) void regdot(const u16* __restrict__ X,
                                              const float* __restrict__ rw,
                                              const float* __restrict__ rb,
                                              float* __restrict__ out, int mode, int param) {
  int wid = (blockIdx.x * 256 + threadIdx.x) >> 6;
  int lane = threadIdx.x & 63;
  int row = wid;
  int k0 = lane * 8;
  uint4 xv = *(const uint4*)&X[(size_t)row * 512 + k0];
  const u16* xp = (const u16*)&xv;
  float p0 = 0.f, p1 = 0.f;
  for (int j = 0; j < 8; j++) {
    float x = b2f(xp[j]);
    p0 += x * rw[(k0 + j) * 2];
    p1 += x * rw[(k0 + j) * 2 + 1];
  }
  for (int o = 32; o; o >>= 1) { p0 += __shfl_down(p0, o); p1 += __shfl_down(p1, o); }
  if (lane == 0) {
    int b, e, td;
    if (mode == 0) { e = param; td = row >> 9; b = row & 511; }
    else           { td = param; e = row >> 9; b = row & 511; }
    size_t off = ((size_t)(b * 8 + e) * 12 + td) * 2;
    out[off]     = p0 + rb[0];
    out[off + 1] = p1 + rb[1];
  }
}

// ---------------------------------------------------------------- encoder attention
// wave per b; writes goal_for_enc into xcat[:,512:640] (carry for next enc step)
__global__ __launch_bounds__(64) void attn_enc_k(const u16* __restrict__ gfeg,  // [12,512,128] bf16
                                                 const float* __restrict__ eaw,
                                                 const float* __restrict__ eab,
                                                 u16* __restrict__ xcat) {
  int b = blockIdx.x;
  int lane = threadIdx.x;
  int h0 = lane, h1 = lane + 64;
  float w0 = eaw[h0], w1 = eaw[h1];
  float bias = eab[0];
  float v0[12], v1[12], lg[12];
  for (int t = 0; t < 12; t++) {
    float a = b2f(gfeg[(size_t)(t * 512 + b) * 128 + h0]);
    float c = b2f(gfeg[(size_t)(t * 512 + b) * 128 + h1]);
    v0[t] = a; v1[t] = c;
    float p = tanhf(a) * w0 + tanhf(c) * w1;
    for (int o = 32; o; o >>= 1) p += __shfl_xor(p, o);
    lg[t] = fmaxf(p + bias, 0.f);
  }
  float m = lg[0];
  for (int t = 1; t < 12; t++) m = fmaxf(m, lg[t]);
  float s = 0.f;
  for (int t = 0; t < 12; t++) { lg[t] = expf(lg[t] - m); s += lg[t]; }
  float inv = 1.f / s;
  float c0 = 0.f, c1 = 0.f;
  for (int t = 0; t < 12; t++) { c0 += lg[t] * inv * v0[t]; c1 += lg[t] * inv * v1[t]; }
  xcat[b * 640 + 512 + h0] = f2b(c0);
  xcat[b * 640 + 512 + h1] = f2b(c1);
}

// ---------------------------------------------------------------- decoder attention (batched)
// wave per (e,b); masked steps s<td contribute logit=relu(da_b), value=0.
__global__ __launch_bounds__(64) void attn_dec_k(const u16* __restrict__ gfd,  // [8,12,512,128] bf16
                                                 const float* __restrict__ daw,
                                                 const float* __restrict__ dab,
                                                 u16* __restrict__ xdec, int td) {
  int row = blockIdx.x;            // e*512 + b
  int lane = threadIdx.x;
  int e = row >> 9, b = row & 511;
  int h0 = lane, h1 = lane + 64;
  float w0 = daw[h0], w1 = daw[h1];
  float bias = dab[0];
  float base = fmaxf(bias, 0.f);
  float v0[12], v1[12], lg[12];
  for (int s = 0; s < 12; s++) {
    if (s < td) { lg[s] = base; v0[s] = 0.f; v1[s] = 0.f; }
    else {
      size_t o = ((size_t)(e * 12 + s) * 512 + b) * 128;
      float a = b2f(gfd[o + h0]);
      float c = b2f(gfd[o + h1]);
      v0[s] = a; v1[s] = c;
      float p = tanhf(a) * w0 + tanhf(c) * w1;
      for (int o2 = 32; o2; o2 >>= 1) p += __shfl_xor(p, o2);
      lg[s] = fmaxf(p + bias, 0.f);
    }
  }
  float m = lg[0];
  for (int s = 1; s < 12; s++) m = fmaxf(m, lg[s]);
  float ssum = 0.f;
  for (int s = 0; s < 12; s++) { lg[s] = expf(lg[s] - m); ssum += lg[s]; }
  float inv = 1.f / ssum;
  float c0 = 0.f, c1 = 0.f;
  for (int s = 0; s < 12; s++) { c0 += lg[s] * inv * v0[s]; c1 += lg[s] * inv * v1[s]; }
  xdec[(size_t)row * 640 + h0] = f2b(c0);
  xdec[(size_t)row * 640 + h1] = f2b(c1);
}

// ================================================================ host
extern "C" void kernel_launch(void* const* d_in, const int* in_sizes, int n_in,
                              void* d_out, int out_size, void* d_ws, size_t ws_size,
                              hipStream_t stream) {
  const float* inp      = (const float*)d_in[0];
  const float* embed_w  = (const float*)d_in[1];
  const float* embed_b  = (const float*)d_in[2];
  const float* reg_w    = (const float*)d_in[3];
  const float* reg_b    = (const float*)d_in[4];
  const float* ea_w     = (const float*)d_in[5];
  const float* ea_b     = (const float*)d_in[6];
  const float* da_w     = (const float*)d_in[7];
  const float* da_b     = (const float*)d_in[8];
  const float* e2g_w    = (const float*)d_in[9];
  const float* e2g_b    = (const float*)d_in[10];
  const float* e2d_w    = (const float*)d_in[11];
  const float* e2d_b    = (const float*)d_in[12];
  const float* gh2i_w   = (const float*)d_in[13];
  const float* gh2i_b   = (const float*)d_in[14];
  const float* dh2i_w   = (const float*)d_in[15];
  const float* dh2i_b   = (const float*)d_in[16];
  const float* gh2t_w   = (const float*)d_in[17];
  const float* gh2t_b   = (const float*)d_in[18];
  const float* g2e_w    = (const float*)d_in[19];
  const float* g2e_b    = (const float*)d_in[20];
  const float* g2d_w    = (const float*)d_in[21];
  const float* g2d_b    = (const float*)d_in[22];
  const float* enc_wih  = (const float*)d_in[23];
  const float* enc_whh  = (const float*)d_in[24];
  const float* enc_bih  = (const float*)d_in[25];
  const float* enc_bhh  = (const float*)d_in[26];
  const float* goal_wih = (const float*)d_in[27];
  const float* goal_whh = (const float*)d_in[28];
  const float* goal_bih = (const float*)d_in[29];
  const float* goal_bhh = (const float*)d_in[30];
  const float* dec_wih  = (const float*)d_in[31];
  const float* dec_whh  = (const float*)d_in[32];
  const float* dec_bih  = (const float*)d_in[33];
  const float* dec_bhh  = (const float*)d_in[34];

  char* ws = (char*)d_ws;
  size_t off = 0;
  auto alloc = [&](size_t bytes) -> char* {
    char* p = ws + off; off += (bytes + 255) & ~(size_t)255; return p;
  };
  // zero-region (contiguous): teh_f32, teh_b, xcat
  float* teh_f   = (float*)alloc(512 * 512 * 4);
  u16*   teh_b   = (u16*)  alloc(512 * 512 * 2);
  u16*   xcat    = (u16*)  alloc(512 * 640 * 2);
  size_t zero_bytes = 512 * 512 * 4 + 512 * 512 * 2 + 512 * 640 * 2;
  u16*   traj    = (u16*)  alloc((size_t)8 * 512 * 512 * 2);
  u16*   gh0     = (u16*)  alloc(512 * 128 * 2);
  u16*   goals   = (u16*)  alloc((size_t)12 * 512 * 128 * 2);
  u16*   ghid    = (u16*)  alloc((size_t)6144 * 512 * 2);
  u16*   gfeg    = (u16*)  alloc((size_t)12 * 512 * 128 * 2);
  u16*   gfd     = (u16*)  alloc((size_t)8 * 12 * 512 * 128 * 2);
  float* dh_f    = (float*)alloc((size_t)4096 * 512 * 4);
  u16*   dh_b    = (u16*)  alloc((size_t)4096 * 512 * 2);
  u16*   xdec    = (u16*)  alloc((size_t)4096 * 640 * 2);
  u16*   giD     = (u16*)  alloc((size_t)4096 * 1536 * 2);   // enc aliases rows 0:512
  u16*   ghD     = (u16*)  alloc((size_t)4096 * 1536 * 2);
  u16*   giE = giD, *ghE = ghD;
  // transposed bf16 weights [N,K]
  u16* enc_wih_t  = (u16*)alloc((size_t)1536 * 640 * 2);
  u16* enc_whh_t  = (u16*)alloc((size_t)1536 * 512 * 2);
  u16* dec_wih_t  = (u16*)alloc((size_t)1536 * 640 * 2);
  u16* dec_whh_t  = (u16*)alloc((size_t)1536 * 512 * 2);
  u16* e2g_t      = (u16*)alloc(128 * 512 * 2);
  u16* e2d_t      = (u16*)alloc(512 * 512 * 2);
  u16* dh2i_t     = (u16*)alloc(512 * 512 * 2);
  u16* gh2t_t     = (u16*)alloc(512 * 128 * 2);
  u16* g2e_t      = (u16*)alloc(128 * 128 * 2);
  u16* g2d_t      = (u16*)alloc(128 * 128 * 2);
  u16* goal_wih_t = (u16*)alloc(384 * 128 * 2);
  u16* goal_whh_t = (u16*)alloc(384 * 128 * 2);
  u16* gh2i_t     = (u16*)alloc(128 * 128 * 2);
  if (off > ws_size) return;  // output stays zero -> visible as round-0-style absmax

  float* out_goal = (float*)d_out;
  float* out_dec  = out_goal + (size_t)512 * 8 * 12 * 2;

  hipMemsetAsync(teh_f, 0, zero_bytes, stream);

  auto T = [&](const float* in, u16* out, int K, int N) {
    transpose_f2b<<<dim3(N / 32, K / 32), 256, 0, stream>>>(in, out, K, N);
  };
  T(enc_wih, enc_wih_t, 640, 1536);
  T(enc_whh, enc_whh_t, 512, 1536);
  T(dec_wih, dec_wih_t, 640, 1536);
  T(dec_whh, dec_whh_t, 512, 1536);
  T(e2g_w, e2g_t, 512, 128);
  T(e2d_w, e2d_t, 512, 512);
  T(dh2i_w, dh2i_t, 512, 512);
  T(gh2t_w, gh2t_t, 128, 512);
  T(g2e_w, g2e_t, 128, 128);
  T(g2d_w, g2d_t, 128, 128);
  T(goal_wih, goal_wih_t, 128, 384);
  T(goal_whh, goal_whh_t, 128, 384);
  T(gh2i_w, gh2i_t, 128, 128);

  embed_kernel<<<8192, 256, 0, stream>>>(inp, embed_w, embed_b, traj);

  auto G = [&](const u16* A, int lda, const u16* W, int ldw, const float* bias,
               u16* Cb, int ldc, float* Cf, int M, int N, int K, int relu) {
    gemm_bt<<<dim3(N / 64, M / 64), 256, 0, stream>>>(A, lda, W, ldw, bias, Cb, ldc, Cf, K, relu);
  };

  // ---------------- encoder chain (serial over ENC)
  for (int e = 0; e < 8; ++e) {
    copy_xt<<<128, 256, 0, stream>>>(traj + (size_t)e * 512 * 512, xcat);
    G(xcat, 640, enc_wih_t, 640, enc_bih, giE, 1536, nullptr, 512, 1536, 640, 0);
    G(teh_b, 512, enc_whh_t, 512, enc_bhh, ghE, 1536, nullptr, 512, 1536, 512, 0);
    gru_pw<<<1024, 256, 0, stream>>>(giE, ghE, teh_f, teh_b, 512);
    G(teh_b, 512, e2g_t, 512, e2g_b, gh0, 128, nullptr, 512, 128, 512, 1);
    G(teh_b, 512, e2d_t, 512, e2d_b, dh_b + (size_t)e * 512 * 512, 512,
      dh_f + (size_t)e * 512 * 512, 512, 512, 512, 1);
    goal_fused<<<32, 256, 0, stream>>>(gh0, goal_wih_t, goal_whh_t, goal_bih, goal_bhh,
                                       gh2i_t, gh2i_b, goals);
    G(goals, 128, gh2t_t, 128, gh2t_b, ghid, 512, nullptr, 6144, 512, 128, 1);
    regdot<<<6144 / 4, 256, 0, stream>>>(ghid, reg_w, reg_b, out_goal, 0, e);
    G(goals, 128, g2d_t, 128, g2d_b, gfd + (size_t)e * 12 * 512 * 128, 128, nullptr, 6144, 128, 128, 1);
    G(goals, 128, g2e_t, 128, g2e_b, gfeg, 128, nullptr, 6144, 128, 128, 1);
    attn_enc_k<<<512, 64, 0, stream>>>(gfeg, ea_w, ea_b, xcat);
  }

  // ---------------- batched decoder (all 8 enc-steps at once, M=4096)
  for (int td = 0; td < 12; ++td) {
    G(dh_b, 512, dh2i_t, 512, dh2i_b, xdec + 128, 640, nullptr, 4096, 512, 512, 1);
    attn_dec_k<<<4096, 64, 0, stream>>>(gfd, da_w, da_b, xdec, td);
    G(xdec, 640, dec_wih_t, 640, dec_bih, giD, 1536, nullptr, 4096, 1536, 640, 0);
    G(dh_b, 512, dec_whh_t, 512, dec_bhh, ghD, 1536, nullptr, 4096, 1536, 512, 0);
    gru_pw<<<8192, 256, 0, stream>>>(giD, ghD, dh_f, dh_b, 4096);
    regdot<<<4096 / 4, 256, 0, stream>>>(dh_b, reg_w, reg_b, out_dec, 1, td);
  }
}

// Round 3
// 1914.684 us; speedup vs baseline: 1.3579x; 1.3579x over previous
//
#include <hip/hip_runtime.h>

// SGNet on MI355X. fp32 inputs/outputs, internal bf16 MFMA pipeline with fp32
// master copies for GRU hidden states.
//  - Weights fp32 -> transposed [N,K] bf16 once per call (gemm_bt pattern,
//    mfma_f32_16x16x32_bf16, C/D layout col=lane&15,row=(lane>>4)*4+r).
//  - Goal GRU (12 steps) fused into one kernel: 16 waves/block, persistent
//    B-fragments in VGPRs, conflict-free LDS padding.
//  - All 8 decoders batched into one M=4096 decoder (decoder is a pure sink).

typedef unsigned short u16;
typedef __attribute__((ext_vector_type(8))) short bf16x8;
typedef __attribute__((ext_vector_type(4))) float f32x4;

static __device__ __forceinline__ float b2f(u16 u) {
  union { float f; unsigned int i; } x; x.i = ((unsigned int)u) << 16; return x.f;
}
static __device__ __forceinline__ u16 f2b(float f) {
  unsigned int u = __float_as_uint(f);
  unsigned int r = (u + 0x7FFFu + ((u >> 16) & 1u)) >> 16;
  return (u16)r;
}
// fast sigmoid / tanh via hw exp (v_exp_f32) + fast divide
static __device__ __forceinline__ float fsig(float x) {
  return __fdividef(1.f, 1.f + __expf(-x));
}
static __device__ __forceinline__ float ftanh(float x) {
  return 1.f - __fdividef(2.f, __expf(2.f * x) + 1.f);
}

// ---------------------------------------------------------------- transpose + cvt
__global__ __launch_bounds__(256) void transpose_f2b(const float* __restrict__ in,
                                                     u16* __restrict__ out,
                                                     int K, int N) {
  __shared__ u16 t[32][33];
  int n0 = blockIdx.x * 32, k0 = blockIdx.y * 32;
  int x = threadIdx.x & 31, y = threadIdx.x >> 5;  // 32 x 8
  for (int i = 0; i < 4; i++) t[y + 8 * i][x] = f2b(in[(size_t)(k0 + y + 8 * i) * N + n0 + x]);
  __syncthreads();
  for (int i = 0; i < 4; i++) out[(size_t)(n0 + y + 8 * i) * K + k0 + x] = t[x][y + 8 * i];
}

// ---------------------------------------------------------------- embed (K=6)
__global__ __launch_bounds__(256) void embed_kernel(const float* __restrict__ inp,
                                                    const float* __restrict__ w,
                                                    const float* __restrict__ bias,
                                                    u16* __restrict__ traj) {
  int t = blockIdx.x * 256 + threadIdx.x;             // 8*512*512
  int h = t & 511, b = (t >> 9) & 511, e = t >> 18;
  float acc = bias[h];
  for (int i = 0; i < 6; i++) acc += inp[(b * 8 + e) * 6 + i] * w[i * 512 + h];
  traj[((e * 512) + b) * 512 + h] = f2b(fmaxf(acc, 0.f));
}

// ---------------------------------------------------------------- copy x_t -> xcat[:,0:512]
__global__ __launch_bounds__(256) void copy_xt(const u16* __restrict__ traj_e,
                                               u16* __restrict__ xcat) {
  int t = blockIdx.x * 256 + threadIdx.x;   // 32768
  int r = t >> 6, c8 = (t & 63) * 8;
  *(uint4*)&xcat[r * 640 + c8] = *(const uint4*)&traj_e[r * 512 + c8];
}

// ---------------------------------------------------------------- generic MFMA GEMM (B^T)
__global__ __launch_bounds__(256) void gemm_bt(const u16* __restrict__ A, int lda,
                                               const u16* __restrict__ W, int ldw,
                                               const float* __restrict__ bias,
                                               u16* __restrict__ Cb, int ldc,
                                               float* __restrict__ Cf,
                                               int K, int relu) {
  __shared__ u16 As[64][72];
  __shared__ u16 Bs[64][72];
  int tid = threadIdx.x;
  int m0 = blockIdx.y * 64, n0 = blockIdx.x * 64;
  int lane = tid & 63, wave = tid >> 6;
  int wr = wave >> 1, wc = wave & 1;
  int mrow = lane & 15, kq = (lane >> 4) * 8;
  f32x4 acc[2][2] = {};

  for (int k0 = 0; k0 < K; k0 += 64) {
    __syncthreads();
    for (int c = tid; c < 512; c += 256) {
      int r = c >> 3, kk = (c & 7) * 8;
      *(uint4*)&As[r][kk] = *(const uint4*)&A[(size_t)(m0 + r) * lda + k0 + kk];
      *(uint4*)&Bs[r][kk] = *(const uint4*)&W[(size_t)(n0 + r) * ldw + k0 + kk];
    }
    __syncthreads();
    for (int ks = 0; ks < 2; ks++) {
      bf16x8 af[2], bf[2];
      for (int i = 0; i < 2; i++) {
        af[i] = *(const bf16x8*)&As[wr * 32 + i * 16 + mrow][ks * 32 + kq];
        bf[i] = *(const bf16x8*)&Bs[wc * 32 + i * 16 + mrow][ks * 32 + kq];
      }
      for (int i = 0; i < 2; i++)
        for (int j = 0; j < 2; j++)
          acc[i][j] = __builtin_amdgcn_mfma_f32_16x16x32_bf16(af[i], bf[j], acc[i][j], 0, 0, 0);
    }
  }
  int col = lane & 15, rq = (lane >> 4) * 4;
  for (int i = 0; i < 2; i++)
    for (int j = 0; j < 2; j++) {
      int n = n0 + wc * 32 + j * 16 + col;
      float bv = bias ? bias[n] : 0.f;
      for (int r = 0; r < 4; r++) {
        int m = m0 + wr * 32 + i * 16 + rq + r;
        float v = acc[i][j][r] + bv;
        if (relu) v = fmaxf(v, 0.f);
        Cb[(size_t)m * ldc + n] = f2b(v);
        if (Cf) Cf[(size_t)m * ldc + n] = v;
      }
    }
}

// ---------------------------------------------------------------- GRU pointwise (H=512)
// 8 elems/thread, vectorized loads; gates bf16 (bias pre-added), fp32 master h.
__global__ __launch_bounds__(256) void gru_pw(const u16* __restrict__ gi,
                                              const u16* __restrict__ gh,
                                              float* __restrict__ hf,
                                              u16* __restrict__ hb, int rows) {
  int t = blockIdx.x * 256 + threadIdx.x;
  if (t >= rows * 64) return;
  int r = t >> 6, j8 = (t & 63) * 8;
  size_t base = (size_t)r * 1536 + j8;
  uint4 ir4 = *(const uint4*)&gi[base];
  uint4 iz4 = *(const uint4*)&gi[base + 512];
  uint4 in4 = *(const uint4*)&gi[base + 1024];
  uint4 hr4 = *(const uint4*)&gh[base];
  uint4 hz4 = *(const uint4*)&gh[base + 512];
  uint4 hn4 = *(const uint4*)&gh[base + 1024];
  const u16* irp = (const u16*)&ir4; const u16* izp = (const u16*)&iz4;
  const u16* inp = (const u16*)&in4; const u16* hrp = (const u16*)&hr4;
  const u16* hzp = (const u16*)&hz4; const u16* hnp = (const u16*)&hn4;
  size_t hoff = (size_t)r * 512 + j8;
  float hv[8];
  *(float4*)&hv[0] = *(const float4*)&hf[hoff];
  *(float4*)&hv[4] = *(const float4*)&hf[hoff + 4];
  u16 hbv[8];
  for (int j = 0; j < 8; j++) {
    float rr = fsig(b2f(irp[j]) + b2f(hrp[j]));
    float zz = fsig(b2f(izp[j]) + b2f(hzp[j]));
    float nn = ftanh(b2f(inp[j]) + rr * b2f(hnp[j]));
    float ho = (1.f - zz) * nn + zz * hv[j];
    hv[j] = ho; hbv[j] = f2b(ho);
  }
  *(float4*)&hf[hoff] = *(const float4*)&hv[0];
  *(float4*)&hf[hoff + 4] = *(const float4*)&hv[4];
  *(uint4*)&hb[hoff] = *(const uint4*)&hbv[0];
}

// ---------------------------------------------------------------- fused goal-GRU loop
// 16 waves/block, 16 rows/block. Persistent B-fragments in VGPRs. Padded LDS.
__global__ __launch_bounds__(1024) void goal_fused(const u16* __restrict__ gh0,      // [512,128]
                                                   const u16* __restrict__ wih_t,    // [384,128]
                                                   const u16* __restrict__ whh_t,    // [384,128]
                                                   const float* __restrict__ bih,    // [384]
                                                   const float* __restrict__ bhh,    // [384]
                                                   const u16* __restrict__ g2i_t,    // [128,128]
                                                   const float* __restrict__ g2i_b,  // [128]
                                                   u16* __restrict__ goals) {        // [12,512,128]
  __shared__ float ghf[16][128];
  __shared__ u16   ghb[16][136];   // stride 136: dword-bank shift 4/row -> 2-way (free)
  __shared__ u16   gib[16][136];
  __shared__ float gi3[16][388];   // stride 388: quad shift 16 banks -> 2-way (free)
  __shared__ float gh3[16][388];
  int tid = threadIdx.x;
  int r0 = blockIdx.x * 16;
  int lane = tid & 63, wave = tid >> 6;       // 16 waves
  int mrow = lane & 15, kq = (lane >> 4) * 8;
  int rq4 = (lane >> 4) * 4;

  // persistent B-fragments: wave handles phase1 tiles {w, w+16, w+32} of 48
  bf16x8 Bf[3][4];
  float  bias1[3];
  int    n0s[3];
  bool   isIv[3];
#pragma unroll
  for (int i = 0; i < 3; i++) {
    int tt = wave + 16 * i;
    bool iI = tt < 24;
    int n0 = (iI ? tt : tt - 24) * 16;
    isIv[i] = iI; n0s[i] = n0;
    const u16* Wt = iI ? wih_t : whh_t;
#pragma unroll
    for (int ks = 0; ks < 4; ks++)
      Bf[i][ks] = *(const bf16x8*)&Wt[(n0 + mrow) * 128 + ks * 32 + kq];
    bias1[i] = (iI ? bih : bhh)[n0 + mrow];
  }
  // phase3 fragments (waves 0..7, tile n0=16w)
  bf16x8 Gf[4];
  float bias3;
  {
    int n0 = (wave & 7) * 16;
#pragma unroll
    for (int ks = 0; ks < 4; ks++)
      Gf[ks] = *(const bf16x8*)&g2i_t[(n0 + mrow) * 128 + ks * 32 + kq];
    bias3 = g2i_b[n0 + mrow];
  }

  for (int idx = tid; idx < 16 * 128; idx += 1024) {
    int m = idx >> 7, j = idx & 127;
    u16 u = gh0[(r0 + m) * 128 + j];
    ghb[m][j] = u; ghf[m][j] = b2f(u); gib[m][j] = 0;
  }
  __syncthreads();

  for (int t = 0; t < 12; t++) {
    // phase 1: gi3 = gi@wih+bih ; gh3 = gh@whh+bhh  (A-frags deduped: 8 ds_read_b128)
    bf16x8 agi[4], agh[4];
#pragma unroll
    for (int ks = 0; ks < 4; ks++) {
      agi[ks] = *(const bf16x8*)&gib[mrow][ks * 32 + kq];
      agh[ks] = *(const bf16x8*)&ghb[mrow][ks * 32 + kq];
    }
#pragma unroll
    for (int i = 0; i < 3; i++) {
      f32x4 acc = {};
#pragma unroll
      for (int ks = 0; ks < 4; ks++)
        acc = __builtin_amdgcn_mfma_f32_16x16x32_bf16(isIv[i] ? agi[ks] : agh[ks],
                                                      Bf[i][ks], acc, 0, 0, 0);
      float* G = isIv[i] ? &gi3[0][0] : &gh3[0][0];
      int n = n0s[i] + mrow;
#pragma unroll
      for (int r = 0; r < 4; r++)
        G[(rq4 + r) * 388 + n] = acc[r] + bias1[i];
    }
    __syncthreads();
    // phase 2: pointwise GRU update + emit goals[t] (2 elems/thread)
    for (int idx = tid; idx < 2048; idx += 1024) {
      int m = idx >> 7, j = idx & 127;
      float rr = fsig(gi3[m][j] + gh3[m][j]);
      float zz = fsig(gi3[m][128 + j] + gh3[m][128 + j]);
      float nn = ftanh(gi3[m][256 + j] + rr * gh3[m][256 + j]);
      float h = ghf[m][j];
      float ho = (1.f - zz) * nn + zz * h;
      ghf[m][j] = ho;
      u16 hb = f2b(ho);
      ghb[m][j] = hb;
      goals[(t * 512 + r0 + m) * 128 + j] = hb;
    }
    __syncthreads();
    // phase 3: gi = relu(gh_new @ gh2i + b)  (waves 0..7)
    if (wave < 8) {
      f32x4 acc = {};
#pragma unroll
      for (int ks = 0; ks < 4; ks++) {
        bf16x8 a = *(const bf16x8*)&ghb[mrow][ks * 32 + kq];
        acc = __builtin_amdgcn_mfma_f32_16x16x32_bf16(a, Gf[ks], acc, 0, 0, 0);
      }
      int n = (wave & 7) * 16 + mrow;
#pragma unroll
      for (int r = 0; r < 4; r++)
        gib[rq4 + r][n] = f2b(fmaxf(acc[r] + bias3, 0.f));
    }
    __syncthreads();
  }
}

// ---------------------------------------------------------------- reg head (wave per row)
__global__ __launch_bounds__(256) void regdot(const u16* __restrict__ X,
                                              const float* __restrict__ rw,
                                              const float* __restrict__ rb,
                                              float* __restrict__ out, int mode, int param) {
  int wid = (blockIdx.x * 256 + threadIdx.x) >> 6;
  int lane = threadIdx.x & 63;
  int row = wid;
  int k0 = lane * 8;
  uint4 xv = *(const uint4*)&X[(size_t)row * 512 + k0];
  const u16* xp = (const u16*)&xv;
  float p0 = 0.f, p1 = 0.f;
  for (int j = 0; j < 8; j++) {
    float x = b2f(xp[j]);
    p0 += x * rw[(k0 + j) * 2];
    p1 += x * rw[(k0 + j) * 2 + 1];
  }
  for (int o = 32; o; o >>= 1) { p0 += __shfl_down(p0, o); p1 += __shfl_down(p1, o); }
  if (lane == 0) {
    int b, e, td;
    if (mode == 0) { e = param; td = row >> 9; b = row & 511; }
    else           { td = param; e = row >> 9; b = row & 511; }
    size_t off = ((size_t)(b * 8 + e) * 12 + td) * 2;
    out[off]     = p0 + rb[0];
    out[off + 1] = p1 + rb[1];
  }
}

// ---------------------------------------------------------------- encoder attention
__global__ __launch_bounds__(64) void attn_enc_k(const u16* __restrict__ gfeg,  // [12,512,128]
                                                 const float* __restrict__ eaw,
                                                 const float* __restrict__ eab,
                                                 u16* __restrict__ xcat) {
  int b = blockIdx.x;
  int lane = threadIdx.x;
  int h0 = lane, h1 = lane + 64;
  float w0 = eaw[h0], w1 = eaw[h1];
  float bias = eab[0];
  float v0[12], v1[12], lg[12];
  for (int t = 0; t < 12; t++) {
    float a = b2f(gfeg[(size_t)(t * 512 + b) * 128 + h0]);
    float c = b2f(gfeg[(size_t)(t * 512 + b) * 128 + h1]);
    v0[t] = a; v1[t] = c;
    float p = ftanh(a) * w0 + ftanh(c) * w1;
    for (int o = 32; o; o >>= 1) p += __shfl_xor(p, o);
    lg[t] = fmaxf(p + bias, 0.f);
  }
  float m = lg[0];
  for (int t = 1; t < 12; t++) m = fmaxf(m, lg[t]);
  float s = 0.f;
  for (int t = 0; t < 12; t++) { lg[t] = __expf(lg[t] - m); s += lg[t]; }
  float inv = __fdividef(1.f, s);
  float c0 = 0.f, c1 = 0.f;
  for (int t = 0; t < 12; t++) { c0 += lg[t] * inv * v0[t]; c1 += lg[t] * inv * v1[t]; }
  xcat[b * 640 + 512 + h0] = f2b(c0);
  xcat[b * 640 + 512 + h1] = f2b(c1);
}

// ---------------------------------------------------------------- decoder attention (batched)
__global__ __launch_bounds__(64) void attn_dec_k(const u16* __restrict__ gfd,  // [8,12,512,128]
                                                 const float* __restrict__ daw,
                                                 const float* __restrict__ dab,
                                                 u16* __restrict__ xdec, int td) {
  int row = blockIdx.x;            // e*512 + b
  int lane = threadIdx.x;
  int e = row >> 9, b = row & 511;
  int h0 = lane, h1 = lane + 64;
  float w0 = daw[h0], w1 = daw[h1];
  float bias = dab[0];
  float base = fmaxf(bias, 0.f);
  float v0[12], v1[12], lg[12];
  for (int s = 0; s < 12; s++) {
    if (s < td) { lg[s] = base; v0[s] = 0.f; v1[s] = 0.f; }
    else {
      size_t o = ((size_t)(e * 12 + s) * 512 + b) * 128;
      float a = b2f(gfd[o + h0]);
      float c = b2f(gfd[o + h1]);
      v0[s] = a; v1[s] = c;
      float p = ftanh(a) * w0 + ftanh(c) * w1;
      for (int o2 = 32; o2; o2 >>= 1) p += __shfl_xor(p, o2);
      lg[s] = fmaxf(p + bias, 0.f);
    }
  }
  float m = lg[0];
  for (int s = 1; s < 12; s++) m = fmaxf(m, lg[s]);
  float ssum = 0.f;
  for (int s = 0; s < 12; s++) { lg[s] = __expf(lg[s] - m); ssum += lg[s]; }
  float inv = __fdividef(1.f, ssum);
  float c0 = 0.f, c1 = 0.f;
  for (int s = 0; s < 12; s++) { c0 += lg[s] * inv * v0[s]; c1 += lg[s] * inv * v1[s]; }
  xdec[(size_t)row * 640 + h0] = f2b(c0);
  xdec[(size_t)row * 640 + h1] = f2b(c1);
}

// ================================================================ host
extern "C" void kernel_launch(void* const* d_in, const int* in_sizes, int n_in,
                              void* d_out, int out_size, void* d_ws, size_t ws_size,
                              hipStream_t stream) {
  const float* inp      = (const float*)d_in[0];
  const float* embed_w  = (const float*)d_in[1];
  const float* embed_b  = (const float*)d_in[2];
  const float* reg_w    = (const float*)d_in[3];
  const float* reg_b    = (const float*)d_in[4];
  const float* ea_w     = (const float*)d_in[5];
  const float* ea_b     = (const float*)d_in[6];
  const float* da_w     = (const float*)d_in[7];
  const float* da_b     = (const float*)d_in[8];
  const float* e2g_w    = (const float*)d_in[9];
  const float* e2g_b    = (const float*)d_in[10];
  const float* e2d_w    = (const float*)d_in[11];
  const float* e2d_b    = (const float*)d_in[12];
  const float* gh2i_w   = (const float*)d_in[13];
  const float* gh2i_b   = (const float*)d_in[14];
  const float* dh2i_w   = (const float*)d_in[15];
  const float* dh2i_b   = (const float*)d_in[16];
  const float* gh2t_w   = (const float*)d_in[17];
  const float* gh2t_b   = (const float*)d_in[18];
  const float* g2e_w    = (const float*)d_in[19];
  const float* g2e_b    = (const float*)d_in[20];
  const float* g2d_w    = (const float*)d_in[21];
  const float* g2d_b    = (const float*)d_in[22];
  const float* enc_wih  = (const float*)d_in[23];
  const float* enc_whh  = (const float*)d_in[24];
  const float* enc_bih  = (const float*)d_in[25];
  const float* enc_bhh  = (const float*)d_in[26];
  const float* goal_wih = (const float*)d_in[27];
  const float* goal_whh = (const float*)d_in[28];
  const float* goal_bih = (const float*)d_in[29];
  const float* goal_bhh = (const float*)d_in[30];
  const float* dec_wih  = (const float*)d_in[31];
  const float* dec_whh  = (const float*)d_in[32];
  const float* dec_bih  = (const float*)d_in[33];
  const float* dec_bhh  = (const float*)d_in[34];

  char* ws = (char*)d_ws;
  size_t off = 0;
  auto alloc = [&](size_t bytes) -> char* {
    char* p = ws + off; off += (bytes + 255) & ~(size_t)255; return p;
  };
  float* teh_f   = (float*)alloc(512 * 512 * 4);
  u16*   teh_b   = (u16*)  alloc(512 * 512 * 2);
  u16*   xcat    = (u16*)  alloc(512 * 640 * 2);
  size_t zero_bytes = 512 * 512 * 4 + 512 * 512 * 2 + 512 * 640 * 2;
  u16*   traj    = (u16*)  alloc((size_t)8 * 512 * 512 * 2);
  u16*   gh0     = (u16*)  alloc(512 * 128 * 2);
  u16*   goals   = (u16*)  alloc((size_t)12 * 512 * 128 * 2);
  u16*   ghid    = (u16*)  alloc((size_t)6144 * 512 * 2);
  u16*   gfeg    = (u16*)  alloc((size_t)12 * 512 * 128 * 2);
  u16*   gfd     = (u16*)  alloc((size_t)8 * 12 * 512 * 128 * 2);
  float* dh_f    = (float*)alloc((size_t)4096 * 512 * 4);
  u16*   dh_b    = (u16*)  alloc((size_t)4096 * 512 * 2);
  u16*   xdec    = (u16*)  alloc((size_t)4096 * 640 * 2);
  u16*   giD     = (u16*)  alloc((size_t)4096 * 1536 * 2);
  u16*   ghD     = (u16*)  alloc((size_t)4096 * 1536 * 2);
  u16*   giE = giD, *ghE = ghD;
  u16* enc_wih_t  = (u16*)alloc((size_t)1536 * 640 * 2);
  u16* enc_whh_t  = (u16*)alloc((size_t)1536 * 512 * 2);
  u16* dec_wih_t  = (u16*)alloc((size_t)1536 * 640 * 2);
  u16* dec_whh_t  = (u16*)alloc((size_t)1536 * 512 * 2);
  u16* e2g_t      = (u16*)alloc(128 * 512 * 2);
  u16* e2d_t      = (u16*)alloc(512 * 512 * 2);
  u16* dh2i_t     = (u16*)alloc(512 * 512 * 2);
  u16* gh2t_t     = (u16*)alloc(512 * 128 * 2);
  u16* g2e_t      = (u16*)alloc(128 * 128 * 2);
  u16* g2d_t      = (u16*)alloc(128 * 128 * 2);
  u16* goal_wih_t = (u16*)alloc(384 * 128 * 2);
  u16* goal_whh_t = (u16*)alloc(384 * 128 * 2);
  u16* gh2i_t     = (u16*)alloc(128 * 128 * 2);
  if (off > ws_size) return;

  float* out_goal = (float*)d_out;
  float* out_dec  = out_goal + (size_t)512 * 8 * 12 * 2;

  hipMemsetAsync(teh_f, 0, zero_bytes, stream);

  auto T = [&](const float* in, u16* out, int K, int N) {
    transpose_f2b<<<dim3(N / 32, K / 32), 256, 0, stream>>>(in, out, K, N);
  };
  T(enc_wih, enc_wih_t, 640, 1536);
  T(enc_whh, enc_whh_t, 512, 1536);
  T(dec_wih, dec_wih_t, 640, 1536);
  T(dec_whh, dec_whh_t, 512, 1536);
  T(e2g_w, e2g_t, 512, 128);
  T(e2d_w, e2d_t, 512, 512);
  T(dh2i_w, dh2i_t, 512, 512);
  T(gh2t_w, gh2t_t, 128, 512);
  T(g2e_w, g2e_t, 128, 128);
  T(g2d_w, g2d_t, 128, 128);
  T(goal_wih, goal_wih_t, 128, 384);
  T(goal_whh, goal_whh_t, 128, 384);
  T(gh2i_w, gh2i_t, 128, 128);

  embed_kernel<<<8192, 256, 0, stream>>>(inp, embed_w, embed_b, traj);

  auto G = [&](const u16* A, int lda, const u16* W, int ldw, const float* bias,
               u16* Cb, int ldc, float* Cf, int M, int N, int K, int relu) {
    gemm_bt<<<dim3(N / 64, M / 64), 256, 0, stream>>>(A, lda, W, ldw, bias, Cb, ldc, Cf, K, relu);
  };

  // ---------------- encoder chain (serial over ENC)
  for (int e = 0; e < 8; ++e) {
    copy_xt<<<128, 256, 0, stream>>>(traj + (size_t)e * 512 * 512, xcat);
    G(xcat, 640, enc_wih_t, 640, enc_bih, giE, 1536, nullptr, 512, 1536, 640, 0);
    G(teh_b, 512, enc_whh_t, 512, enc_bhh, ghE, 1536, nullptr, 512, 1536, 512, 0);
    gru_pw<<<128, 256, 0, stream>>>(giE, ghE, teh_f, teh_b, 512);
    G(teh_b, 512, e2g_t, 512, e2g_b, gh0, 128, nullptr, 512, 128, 512, 1);
    G(teh_b, 512, e2d_t, 512, e2d_b, dh_b + (size_t)e * 512 * 512, 512,
      dh_f + (size_t)e * 512 * 512, 512, 512, 512, 1);
    goal_fused<<<32, 1024, 0, stream>>>(gh0, goal_wih_t, goal_whh_t, goal_bih, goal_bhh,
                                        gh2i_t, gh2i_b, goals);
    G(goals, 128, gh2t_t, 128, gh2t_b, ghid, 512, nullptr, 6144, 512, 128, 1);
    regdot<<<6144 / 4, 256, 0, stream>>>(ghid, reg_w, reg_b, out_goal, 0, e);
    G(goals, 128, g2d_t, 128, g2d_b, gfd + (size_t)e * 12 * 512 * 128, 128, nullptr, 6144, 128, 128, 1);
    G(goals, 128, g2e_t, 128, g2e_b, gfeg, 128, nullptr, 6144, 128, 128, 1);
    attn_enc_k<<<512, 64, 0, stream>>>(gfeg, ea_w, ea_b, xcat);
  }

  // ---------------- batched decoder (all 8 enc-steps at once, M=4096)
  for (int td = 0; td < 12; ++td) {
    G(dh_b, 512, dh2i_t, 512, dh2i_b, xdec + 128, 640, nullptr, 4096, 512, 512, 1);
    attn_dec_k<<<4096, 64, 0, stream>>>(gfd, da_w, da_b, xdec, td);
    G(xdec, 640, dec_wih_t, 640, dec_bih, giD, 1536, nullptr, 4096, 1536, 640, 0);
    G(dh_b, 512, dec_whh_t, 512, dec_bhh, ghD, 1536, nullptr, 4096, 1536, 512, 0);
    gru_pw<<<1024, 256, 0, stream>>>(giD, ghD, dh_f, dh_b, 4096);
    regdot<<<4096 / 4, 256, 0, stream>>>(dh_b, reg_w, reg_b, out_dec, 1, td);
  }
}

// Round 4
// 1523.814 us; speedup vs baseline: 1.7063x; 1.2565x over previous
//
#include <hip/hip_runtime.h>

// SGNet on MI355X. fp32 in/out, internal bf16 MFMA pipeline, fp32 master GRU
// states. Round-4: 128x128-tile GEMM, dual-descriptor launches, deferred
// batched encoder sinks, goal_mega (goal GRU + g2e + enc attention fused).

typedef unsigned short u16;
typedef __attribute__((ext_vector_type(8))) short bf16x8;
typedef __attribute__((ext_vector_type(4))) float f32x4;

static __device__ __forceinline__ float b2f(u16 u) {
  union { float f; unsigned int i; } x; x.i = ((unsigned int)u) << 16; return x.f;
}
static __device__ __forceinline__ u16 f2b(float f) {
  unsigned int u = __float_as_uint(f);
  unsigned int r = (u + 0x7FFFu + ((u >> 16) & 1u)) >> 16;
  return (u16)r;
}
static __device__ __forceinline__ float fsig(float x) {
  return __fdividef(1.f, 1.f + __expf(-x));
}
static __device__ __forceinline__ float ftanh(float x) {
  return 1.f - __fdividef(2.f, __expf(2.f * x) + 1.f);
}

// ---------------------------------------------------------------- transpose + cvt
__global__ __launch_bounds__(256) void transpose_f2b(const float* __restrict__ in,
                                                     u16* __restrict__ out,
                                                     int K, int N) {
  __shared__ u16 t[32][33];
  int n0 = blockIdx.x * 32, k0 = blockIdx.y * 32;
  int x = threadIdx.x & 31, y = threadIdx.x >> 5;  // 32 x 8
  for (int i = 0; i < 4; i++) t[y + 8 * i][x] = f2b(in[(size_t)(k0 + y + 8 * i) * N + n0 + x]);
  __syncthreads();
  for (int i = 0; i < 4; i++) out[(size_t)(n0 + y + 8 * i) * K + k0 + x] = t[x][y + 8 * i];
}

// ---------------------------------------------------------------- embed (K=6)
__global__ __launch_bounds__(256) void embed_kernel(const float* __restrict__ inp,
                                                    const float* __restrict__ w,
                                                    const float* __restrict__ bias,
                                                    u16* __restrict__ traj) {
  int t = blockIdx.x * 256 + threadIdx.x;             // 8*512*512
  int h = t & 511, b = (t >> 9) & 511, e = t >> 18;
  float acc = bias[h];
  for (int i = 0; i < 6; i++) acc += inp[(b * 8 + e) * 6 + i] * w[i * 512 + h];
  traj[((e * 512) + b) * 512 + h] = f2b(fmaxf(acc, 0.f));
}

// ---------------------------------------------------------------- copy x_t -> xcat[:,0:512]
__global__ __launch_bounds__(256) void copy_xt(const u16* __restrict__ traj_e,
                                               u16* __restrict__ xcat) {
  int t = blockIdx.x * 256 + threadIdx.x;   // 32768
  int r = t >> 6, c8 = (t & 63) * 8;
  *(uint4*)&xcat[r * 640 + c8] = *(const uint4*)&traj_e[r * 512 + c8];
}

// ---------------------------------------------------------------- 64-tile MFMA GEMM (B^T)
__global__ __launch_bounds__(256) void gemm_bt(const u16* __restrict__ A, int lda,
                                               const u16* __restrict__ W, int ldw,
                                               const float* __restrict__ bias,
                                               u16* __restrict__ Cb, int ldc,
                                               float* __restrict__ Cf,
                                               int K, int relu) {
  __shared__ u16 As[64][72];
  __shared__ u16 Bs[64][72];
  int tid = threadIdx.x;
  int m0 = blockIdx.y * 64, n0 = blockIdx.x * 64;
  int lane = tid & 63, wave = tid >> 6;
  int wr = wave >> 1, wc = wave & 1;
  int mrow = lane & 15, kq = (lane >> 4) * 8;
  f32x4 acc[2][2] = {};

  for (int k0 = 0; k0 < K; k0 += 64) {
    __syncthreads();
    for (int c = tid; c < 512; c += 256) {
      int r = c >> 3, kk = (c & 7) * 8;
      *(uint4*)&As[r][kk] = *(const uint4*)&A[(size_t)(m0 + r) * lda + k0 + kk];
      *(uint4*)&Bs[r][kk] = *(const uint4*)&W[(size_t)(n0 + r) * ldw + k0 + kk];
    }
    __syncthreads();
    for (int ks = 0; ks < 2; ks++) {
      bf16x8 af[2], bf[2];
      for (int i = 0; i < 2; i++) {
        af[i] = *(const bf16x8*)&As[wr * 32 + i * 16 + mrow][ks * 32 + kq];
        bf[i] = *(const bf16x8*)&Bs[wc * 32 + i * 16 + mrow][ks * 32 + kq];
      }
      for (int i = 0; i < 2; i++)
        for (int j = 0; j < 2; j++)
          acc[i][j] = __builtin_amdgcn_mfma_f32_16x16x32_bf16(af[i], bf[j], acc[i][j], 0, 0, 0);
    }
  }
  int col = lane & 15, rq = (lane >> 4) * 4;
  for (int i = 0; i < 2; i++)
    for (int j = 0; j < 2; j++) {
      int n = n0 + wc * 32 + j * 16 + col;
      float bv = bias ? bias[n] : 0.f;
      for (int r = 0; r < 4; r++) {
        int m = m0 + wr * 32 + i * 16 + rq + r;
        float v = acc[i][j][r] + bv;
        if (relu) v = fmaxf(v, 0.f);
        Cb[(size_t)m * ldc + n] = f2b(v);
        if (Cf) Cf[(size_t)m * ldc + n] = v;
      }
    }
}

// ---------------------------------------------------------------- 128-tile MFMA GEMM
// Dual-descriptor: blockIdx.z selects d0/d1 (independent GEMMs, same M).
// Column routing: cols >= route_n go to Cb2 (ldc2), for concatenated weights.
struct GDesc {
  const u16* A; int lda;
  const u16* W; int ldw;
  const float* bias;
  u16* Cb; int ldc;
  float* Cf;
  u16* Cb2; int ldc2; int route_n;
  int K; int relu; int nblk;
};

__global__ __launch_bounds__(256) void gemm128(GDesc d0, GDesc d1) {
  GDesc d = (blockIdx.z == 0) ? d0 : d1;
  if ((int)blockIdx.x >= d.nblk) return;
  __shared__ u16 As[128][72];   // row = 144B (16B-aligned); pad -> 2-way banks (free)
  __shared__ u16 Bs[128][72];
  int tid = threadIdx.x;
  int m0 = blockIdx.y * 128, n0 = blockIdx.x * 128;
  int lane = tid & 63, wave = tid >> 6;
  int wr = wave >> 1, wc = wave & 1;
  int mrow = lane & 15, kq = (lane >> 4) * 8;
  int srow = tid >> 3, scol = (tid & 7) * 8;
  f32x4 acc[4][4] = {};

  for (int k0 = 0; k0 < d.K; k0 += 64) {
    __syncthreads();
#pragma unroll
    for (int p = 0; p < 4; p++) {
      int r = srow + p * 32;
      *(uint4*)&As[r][scol] = *(const uint4*)&d.A[(size_t)(m0 + r) * d.lda + k0 + scol];
      *(uint4*)&Bs[r][scol] = *(const uint4*)&d.W[(size_t)(n0 + r) * d.ldw + k0 + scol];
    }
    __syncthreads();
#pragma unroll
    for (int ks = 0; ks < 2; ks++) {
      bf16x8 af[4], bf[4];
#pragma unroll
      for (int i = 0; i < 4; i++) {
        af[i] = *(const bf16x8*)&As[wr * 64 + i * 16 + mrow][ks * 32 + kq];
        bf[i] = *(const bf16x8*)&Bs[wc * 64 + i * 16 + mrow][ks * 32 + kq];
      }
#pragma unroll
      for (int i = 0; i < 4; i++)
#pragma unroll
        for (int j = 0; j < 4; j++)
          acc[i][j] = __builtin_amdgcn_mfma_f32_16x16x32_bf16(af[i], bf[j], acc[i][j], 0, 0, 0);
    }
  }
  int col = lane & 15, rq = (lane >> 4) * 4;
#pragma unroll
  for (int j = 0; j < 4; j++) {
    int n = n0 + wc * 64 + j * 16 + col;
    float bv = d.bias ? d.bias[n] : 0.f;
    bool r2 = (n >= d.route_n);
    u16* cb = r2 ? d.Cb2 : d.Cb;
    int ldc = r2 ? d.ldc2 : d.ldc;
    int nn = r2 ? n - d.route_n : n;
#pragma unroll
    for (int i = 0; i < 4; i++)
#pragma unroll
      for (int r = 0; r < 4; r++) {
        int m = m0 + wr * 64 + i * 16 + rq + r;
        float v = acc[i][j][r] + bv;
        if (d.relu) v = fmaxf(v, 0.f);
        cb[(size_t)m * ldc + nn] = f2b(v);
        if (d.Cf) d.Cf[(size_t)m * d.ldc + n] = v;
      }
  }
}

// ---------------------------------------------------------------- GRU pointwise (H=512)
__global__ __launch_bounds__(256) void gru_pw(const u16* __restrict__ gi,
                                              const u16* __restrict__ gh,
                                              float* __restrict__ hf,
                                              u16* __restrict__ hb, int rows) {
  int t = blockIdx.x * 256 + threadIdx.x;
  if (t >= rows * 64) return;
  int r = t >> 6, j8 = (t & 63) * 8;
  size_t base = (size_t)r * 1536 + j8;
  uint4 ir4 = *(const uint4*)&gi[base];
  uint4 iz4 = *(const uint4*)&gi[base + 512];
  uint4 in4 = *(const uint4*)&gi[base + 1024];
  uint4 hr4 = *(const uint4*)&gh[base];
  uint4 hz4 = *(const uint4*)&gh[base + 512];
  uint4 hn4 = *(const uint4*)&gh[base + 1024];
  const u16* irp = (const u16*)&ir4; const u16* izp = (const u16*)&iz4;
  const u16* inp = (const u16*)&in4; const u16* hrp = (const u16*)&hr4;
  const u16* hzp = (const u16*)&hz4; const u16* hnp = (const u16*)&hn4;
  size_t hoff = (size_t)r * 512 + j8;
  float hv[8];
  *(float4*)&hv[0] = *(const float4*)&hf[hoff];
  *(float4*)&hv[4] = *(const float4*)&hf[hoff + 4];
  u16 hbv[8];
  for (int j = 0; j < 8; j++) {
    float rr = fsig(b2f(irp[j]) + b2f(hrp[j]));
    float zz = fsig(b2f(izp[j]) + b2f(hzp[j]));
    float nn = ftanh(b2f(inp[j]) + rr * b2f(hnp[j]));
    float ho = (1.f - zz) * nn + zz * hv[j];
    hv[j] = ho; hbv[j] = f2b(ho);
  }
  *(float4*)&hf[hoff] = *(const float4*)&hv[0];
  *(float4*)&hf[hoff + 4] = *(const float4*)&hv[4];
  *(uint4*)&hb[hoff] = *(const uint4*)&hbv[0];
}

// ---------------------------------------------------------------- goal_mega
// 12-step goal GRU + g2e (idle waves of phase 3) + encoder attention, fused.
// 16 waves/block, 16 rows/block, gfe kept in LDS (115 KB total, gfx950 ok).
__global__ __launch_bounds__(1024) void goal_mega(const u16* __restrict__ gh0,      // [512,128]
                                                  const u16* __restrict__ wih_t,    // [384,128]
                                                  const u16* __restrict__ whh_t,    // [384,128]
                                                  const float* __restrict__ bih,    // [384]
                                                  const float* __restrict__ bhh,    // [384]
                                                  const u16* __restrict__ g2i_t,    // [128,128]
                                                  const float* __restrict__ g2i_b,  // [128]
                                                  const u16* __restrict__ g2e_t,    // [128,128]
                                                  const float* __restrict__ g2e_b,  // [128]
                                                  const float* __restrict__ eaw,    // [128]
                                                  const float* __restrict__ eab,    // [1]
                                                  u16* __restrict__ goals,          // [12,512,128] (e-slice)
                                                  u16* __restrict__ xcat) {         // [512,640]
  __shared__ float ghf[16][128];
  __shared__ u16   ghb[16][136];   // pad: 2-way banks (free)
  __shared__ u16   gib[16][136];
  __shared__ float gi3[16][388];
  __shared__ float gh3[16][388];
  __shared__ u16   gfe_l[12][16][128];
  int tid = threadIdx.x;
  int r0 = blockIdx.x * 16;
  int lane = tid & 63, wave = tid >> 6;       // 16 waves
  int mrow = lane & 15, kq = (lane >> 4) * 8;
  int rq4 = (lane >> 4) * 4;

  // persistent B-fragments: phase-1 tiles {w, w+16, w+32} of 48
  bf16x8 Bf[3][4];
  float  bias1[3];
  int    n0s[3];
  bool   isIv[3];
#pragma unroll
  for (int i = 0; i < 3; i++) {
    int tt = wave + 16 * i;
    bool iI = tt < 24;
    int n0 = (iI ? tt : tt - 24) * 16;
    isIv[i] = iI; n0s[i] = n0;
    const u16* Wt = iI ? wih_t : whh_t;
#pragma unroll
    for (int ks = 0; ks < 4; ks++)
      Bf[i][ks] = *(const bf16x8*)&Wt[(n0 + mrow) * 128 + ks * 32 + kq];
    bias1[i] = (iI ? bih : bhh)[n0 + mrow];
  }
  // phase-3 fragments: waves 0-7 -> g2i, waves 8-15 -> g2e
  bf16x8 Gf[4];
  float bias3;
  {
    const u16* W3 = (wave < 8) ? g2i_t : g2e_t;
    const float* B3 = (wave < 8) ? g2i_b : g2e_b;
    int n0 = (wave & 7) * 16;
#pragma unroll
    for (int ks = 0; ks < 4; ks++)
      Gf[ks] = *(const bf16x8*)&W3[(n0 + mrow) * 128 + ks * 32 + kq];
    bias3 = B3[n0 + mrow];
  }

  for (int idx = tid; idx < 16 * 128; idx += 1024) {
    int m = idx >> 7, j = idx & 127;
    u16 u = gh0[(r0 + m) * 128 + j];
    ghb[m][j] = u; ghf[m][j] = b2f(u); gib[m][j] = 0;
  }
  __syncthreads();

  for (int t = 0; t < 12; t++) {
    // phase 1: gi3 = gi@wih+bih ; gh3 = gh@whh+bhh
    bf16x8 agi[4], agh[4];
#pragma unroll
    for (int ks = 0; ks < 4; ks++) {
      agi[ks] = *(const bf16x8*)&gib[mrow][ks * 32 + kq];
      agh[ks] = *(const bf16x8*)&ghb[mrow][ks * 32 + kq];
    }
#pragma unroll
    for (int i = 0; i < 3; i++) {
      f32x4 acc = {};
#pragma unroll
      for (int ks = 0; ks < 4; ks++)
        acc = __builtin_amdgcn_mfma_f32_16x16x32_bf16(isIv[i] ? agi[ks] : agh[ks],
                                                      Bf[i][ks], acc, 0, 0, 0);
      float* G = isIv[i] ? &gi3[0][0] : &gh3[0][0];
      int n = n0s[i] + mrow;
#pragma unroll
      for (int r = 0; r < 4; r++)
        G[(rq4 + r) * 388 + n] = acc[r] + bias1[i];
    }
    __syncthreads();
    // phase 2: pointwise GRU + emit goals[t]
    for (int idx = tid; idx < 2048; idx += 1024) {
      int m = idx >> 7, j = idx & 127;
      float rr = fsig(gi3[m][j] + gh3[m][j]);
      float zz = fsig(gi3[m][128 + j] + gh3[m][128 + j]);
      float nn = ftanh(gi3[m][256 + j] + rr * gh3[m][256 + j]);
      float h = ghf[m][j];
      float ho = (1.f - zz) * nn + zz * h;
      ghf[m][j] = ho;
      u16 hb = f2b(ho);
      ghb[m][j] = hb;
      goals[(t * 512 + r0 + m) * 128 + j] = hb;
    }
    __syncthreads();
    // phase 3: waves 0-7: gib = relu(gh@g2i+b); waves 8-15: gfe_l[t] = relu(gh@g2e+b)
    {
      f32x4 acc = {};
#pragma unroll
      for (int ks = 0; ks < 4; ks++) {
        bf16x8 a = *(const bf16x8*)&ghb[mrow][ks * 32 + kq];
        acc = __builtin_amdgcn_mfma_f32_16x16x32_bf16(a, Gf[ks], acc, 0, 0, 0);
      }
      int n = (wave & 7) * 16 + mrow;
      if (wave < 8) {
#pragma unroll
        for (int r = 0; r < 4; r++)
          gib[rq4 + r][n] = f2b(fmaxf(acc[r] + bias3, 0.f));
      } else {
#pragma unroll
        for (int r = 0; r < 4; r++)
          gfe_l[t][rq4 + r][n] = f2b(fmaxf(acc[r] + bias3, 0.f));
      }
    }
    __syncthreads();
  }

  // encoder attention over the block's 16 rows (wave w -> row w)
  {
    int m = wave;
    float w0 = eaw[lane], w1 = eaw[lane + 64];
    float eb = eab[0];
    float v0[12], v1[12], lg[12];
#pragma unroll
    for (int t = 0; t < 12; t++) {
      float a = b2f(gfe_l[t][m][lane]);
      float c = b2f(gfe_l[t][m][lane + 64]);
      v0[t] = a; v1[t] = c;
      float p = ftanh(a) * w0 + ftanh(c) * w1;
      for (int o = 32; o; o >>= 1) p += __shfl_xor(p, o);
      lg[t] = fmaxf(p + eb, 0.f);
    }
    float mx = lg[0];
#pragma unroll
    for (int t = 1; t < 12; t++) mx = fmaxf(mx, lg[t]);
    float s = 0.f;
#pragma unroll
    for (int t = 0; t < 12; t++) { lg[t] = __expf(lg[t] - mx); s += lg[t]; }
    float inv = __fdividef(1.f, s);
    float c0 = 0.f, c1 = 0.f;
#pragma unroll
    for (int t = 0; t < 12; t++) { c0 += lg[t] * inv * v0[t]; c1 += lg[t] * inv * v1[t]; }
    xcat[(r0 + m) * 640 + 512 + lane] = f2b(c0);
    xcat[(r0 + m) * 640 + 512 + lane + 64] = f2b(c1);
  }
}

// ---------------------------------------------------------------- reg head (wave per row)
// mode 0: unused. mode 1: decoder (row=e*512+b, td=param).
// mode 2: batched goal (row=(e*12+t)*512+b).
__global__ __launch_bounds__(256) void regdot(const u16* __restrict__ X,
                                              const float* __restrict__ rw,
                                              const float* __restrict__ rb,
                                              float* __restrict__ out, int mode, int param) {
  int wid = (blockIdx.x * 256 + threadIdx.x) >> 6;
  int lane = threadIdx.x & 63;
  int row = wid;
  int k0 = lane * 8;
  uint4 xv = *(const uint4*)&X[(size_t)row * 512 + k0];
  const u16* xp = (const u16*)&xv;
  float p0 = 0.f, p1 = 0.f;
  for (int j = 0; j < 8; j++) {
    float x = b2f(xp[j]);
    p0 += x * rw[(k0 + j) * 2];
    p1 += x * rw[(k0 + j) * 2 + 1];
  }
  for (int o = 32; o; o >>= 1) { p0 += __shfl_down(p0, o); p1 += __shfl_down(p1, o); }
  if (lane == 0) {
    int b, e, td;
    if (mode == 1) { td = param; e = row >> 9; b = row & 511; }
    else { int s = row >> 9; e = s / 12; td = s - e * 12; b = row & 511; }
    size_t off = ((size_t)(b * 8 + e) * 12 + td) * 2;
    out[off]     = p0 + rb[0];
    out[off + 1] = p1 + rb[1];
  }
}

// ---------------------------------------------------------------- decoder attention (batched)
__global__ __launch_bounds__(64) void attn_dec_k(const u16* __restrict__ gfd,  // [8,12,512,128]
                                                 const float* __restrict__ daw,
                                                 const float* __restrict__ dab,
                                                 u16* __restrict__ xdec, int td) {
  int row = blockIdx.x;            // e*512 + b
  int lane = threadIdx.x;
  int e = row >> 9, b = row & 511;
  int h0 = lane, h1 = lane + 64;
  float w0 = daw[h0], w1 = daw[h1];
  float bias = dab[0];
  float base = fmaxf(bias, 0.f);
  float v0[12], v1[12], lg[12];
  for (int s = 0; s < 12; s++) {
    if (s < td) { lg[s] = base; v0[s] = 0.f; v1[s] = 0.f; }
    else {
      size_t o = ((size_t)(e * 12 + s) * 512 + b) * 128;
      float a = b2f(gfd[o + h0]);
      float c = b2f(gfd[o + h1]);
      v0[s] = a; v1[s] = c;
      float p = ftanh(a) * w0 + ftanh(c) * w1;
      for (int o2 = 32; o2; o2 >>= 1) p += __shfl_xor(p, o2);
      lg[s] = fmaxf(p + bias, 0.f);
    }
  }
  float m = lg[0];
  for (int s = 1; s < 12; s++) m = fmaxf(m, lg[s]);
  float ssum = 0.f;
  for (int s = 0; s < 12; s++) { lg[s] = __expf(lg[s] - m); ssum += lg[s]; }
  float inv = __fdividef(1.f, ssum);
  float c0 = 0.f, c1 = 0.f;
  for (int s = 0; s < 12; s++) { c0 += lg[s] * inv * v0[s]; c1 += lg[s] * inv * v1[s]; }
  xdec[(size_t)row * 640 + h0] = f2b(c0);
  xdec[(size_t)row * 640 + h1] = f2b(c1);
}

// ================================================================ host
extern "C" void kernel_launch(void* const* d_in, const int* in_sizes, int n_in,
                              void* d_out, int out_size, void* d_ws, size_t ws_size,
                              hipStream_t stream) {
  const float* inp      = (const float*)d_in[0];
  const float* embed_w  = (const float*)d_in[1];
  const float* embed_b  = (const float*)d_in[2];
  const float* reg_w    = (const float*)d_in[3];
  const float* reg_b    = (const float*)d_in[4];
  const float* ea_w     = (const float*)d_in[5];
  const float* ea_b     = (const float*)d_in[6];
  const float* da_w     = (const float*)d_in[7];
  const float* da_b     = (const float*)d_in[8];
  const float* e2g_w    = (const float*)d_in[9];
  const float* e2g_b    = (const float*)d_in[10];
  const float* e2d_w    = (const float*)d_in[11];
  const float* e2d_b    = (const float*)d_in[12];
  const float* gh2i_w   = (const float*)d_in[13];
  const float* gh2i_b   = (const float*)d_in[14];
  const float* dh2i_w   = (const float*)d_in[15];
  const float* dh2i_b   = (const float*)d_in[16];
  const float* gh2t_w   = (const float*)d_in[17];
  const float* gh2t_b   = (const float*)d_in[18];
  const float* g2e_w    = (const float*)d_in[19];
  const float* g2e_b    = (const float*)d_in[20];
  const float* g2d_w    = (const float*)d_in[21];
  const float* g2d_b    = (const float*)d_in[22];
  const float* enc_wih  = (const float*)d_in[23];
  const float* enc_whh  = (const float*)d_in[24];
  const float* enc_bih  = (const float*)d_in[25];
  const float* enc_bhh  = (const float*)d_in[26];
  const float* goal_wih = (const float*)d_in[27];
  const float* goal_whh = (const float*)d_in[28];
  const float* goal_bih = (const float*)d_in[29];
  const float* goal_bhh = (const float*)d_in[30];
  const float* dec_wih  = (const float*)d_in[31];
  const float* dec_whh  = (const float*)d_in[32];
  const float* dec_bih  = (const float*)d_in[33];
  const float* dec_bhh  = (const float*)d_in[34];

  char* ws = (char*)d_ws;
  size_t off = 0;
  auto alloc = [&](size_t bytes) -> char* {
    char* p = ws + off; off += (bytes + 255) & ~(size_t)255; return p;
  };
  const size_t TSZ = 512 * 512;
  float* teh_f    = (float*)alloc(TSZ * 4);                    // fp32 master teh
  u16*   teh_hist = (u16*)  alloc(9 * TSZ * 2);                // slot0 zero, slot e+1 = teh after step e
  u16*   xcat     = (u16*)  alloc(512 * 640 * 2);
  u16*   traj     = (u16*)  alloc((size_t)8 * TSZ * 2);
  u16*   gh0      = (u16*)  alloc(512 * 128 * 2);
  u16*   goals_all= (u16*)  alloc((size_t)8 * 6144 * 128 * 2); // [8][12,512,128]
  u16*   ghid     = (u16*)  alloc((size_t)49152 * 512 * 2);
  u16*   gfd      = (u16*)  alloc((size_t)49152 * 128 * 2);    // [8,12,512,128]
  float* dh_f     = (float*)alloc((size_t)4096 * 512 * 4);
  u16*   dh_b     = (u16*)  alloc((size_t)4096 * 512 * 2);
  u16*   xdec     = (u16*)  alloc((size_t)4096 * 640 * 2);
  u16*   giD      = (u16*)  alloc((size_t)4096 * 1536 * 2);
  u16*   ghD      = (u16*)  alloc((size_t)4096 * 1536 * 2);
  u16*   giE = giD, *ghE = ghD;                                // enc aliases rows 0:512
  u16* enc_wih_t  = (u16*)alloc((size_t)1536 * 640 * 2);
  u16* enc_whh_t  = (u16*)alloc((size_t)1536 * 512 * 2);
  u16* dec_wih_t  = (u16*)alloc((size_t)1536 * 640 * 2);
  u16* dec_whh_t  = (u16*)alloc((size_t)1536 * 512 * 2);
  u16* e2g_t      = (u16*)alloc(128 * 512 * 2);
  u16* e2d_t      = (u16*)alloc(512 * 512 * 2);
  u16* dh2i_t     = (u16*)alloc(512 * 512 * 2);
  u16* head_t     = (u16*)alloc(640 * 128 * 2);   // rows 0-511: gh2t_t, 512-639: g2d_t
  u16* g2e_t      = (u16*)alloc(128 * 128 * 2);
  u16* goal_wih_t = (u16*)alloc(384 * 128 * 2);
  u16* goal_whh_t = (u16*)alloc(384 * 128 * 2);
  u16* gh2i_t     = (u16*)alloc(128 * 128 * 2);
  float* head_b   = (float*)alloc(640 * 4);
  if (off > ws_size) return;

  float* out_goal = (float*)d_out;
  float* out_dec  = out_goal + (size_t)512 * 8 * 12 * 2;

  // zero teh_f + teh_hist slot0 (contiguous) and xcat
  hipMemsetAsync(teh_f, 0, TSZ * 4 + TSZ * 2, stream);
  hipMemsetAsync(xcat, 0, 512 * 640 * 2, stream);

  auto T = [&](const float* in, u16* out, int K, int N) {
    transpose_f2b<<<dim3(N / 32, K / 32), 256, 0, stream>>>(in, out, K, N);
  };
  T(enc_wih, enc_wih_t, 640, 1536);
  T(enc_whh, enc_whh_t, 512, 1536);
  T(dec_wih, dec_wih_t, 640, 1536);
  T(dec_whh, dec_whh_t, 512, 1536);
  T(e2g_w, e2g_t, 512, 128);
  T(e2d_w, e2d_t, 512, 512);
  T(dh2i_w, dh2i_t, 512, 512);
  T(gh2t_w, head_t, 128, 512);
  T(g2d_w, head_t + 512 * 128, 128, 128);
  T(g2e_w, g2e_t, 128, 128);
  T(goal_wih, goal_wih_t, 128, 384);
  T(goal_whh, goal_whh_t, 128, 384);
  T(gh2i_w, gh2i_t, 128, 128);
  hipMemcpyAsync(head_b, gh2t_b, 512 * 4, hipMemcpyDeviceToDevice, stream);
  hipMemcpyAsync(head_b + 512, g2d_b, 128 * 4, hipMemcpyDeviceToDevice, stream);

  embed_kernel<<<8192, 256, 0, stream>>>(inp, embed_w, embed_b, traj);

  const int FAR = 1 << 30;
  auto G64 = [&](const u16* A, int lda, const u16* W, int ldw, const float* bias,
                 u16* Cb, int ldc, float* Cf, int M, int N, int K, int relu) {
    gemm_bt<<<dim3(N / 64, M / 64), 256, 0, stream>>>(A, lda, W, ldw, bias, Cb, ldc, Cf, K, relu);
  };

  // ---------------- encoder chain (serial over ENC)
  for (int e = 0; e < 8; ++e) {
    copy_xt<<<128, 256, 0, stream>>>(traj + (size_t)e * TSZ, xcat);
    GDesc dgi{xcat, 640, enc_wih_t, 640, enc_bih, giE, 1536, nullptr,
              nullptr, 0, FAR, 640, 0, 12};
    GDesc dgh{teh_hist + e * TSZ, 512, enc_whh_t, 512, enc_bhh, ghE, 1536, nullptr,
              nullptr, 0, FAR, 512, 0, 12};
    gemm128<<<dim3(12, 4, 2), 256, 0, stream>>>(dgi, dgh);
    gru_pw<<<128, 256, 0, stream>>>(giE, ghE, teh_f, teh_hist + (e + 1) * TSZ, 512);
    G64(teh_hist + (e + 1) * TSZ, 512, e2g_t, 512, e2g_b, gh0, 128, nullptr, 512, 128, 512, 1);
    goal_mega<<<32, 1024, 0, stream>>>(gh0, goal_wih_t, goal_whh_t, goal_bih, goal_bhh,
                                       gh2i_t, gh2i_b, g2e_t, g2e_b, ea_w, ea_b,
                                       goals_all + (size_t)e * 6144 * 128, xcat);
  }

  // ---------------- deferred batched encoder sinks
  {
    GDesc de2d{teh_hist + TSZ, 512, e2d_t, 512, e2d_b, dh_b, 512, dh_f,
               nullptr, 0, FAR, 512, 1, 4};
    gemm128<<<dim3(4, 32, 1), 256, 0, stream>>>(de2d, de2d);
    GDesc dhead{goals_all, 128, head_t, 128, head_b, ghid, 512, nullptr,
                gfd, 128, 512, 128, 1, 5};
    gemm128<<<dim3(5, 384, 1), 256, 0, stream>>>(dhead, dhead);
    regdot<<<12288, 256, 0, stream>>>(ghid, reg_w, reg_b, out_goal, 2, 0);
  }

  // ---------------- batched decoder (all 8 enc-steps at once, M=4096)
  for (int td = 0; td < 12; ++td) {
    attn_dec_k<<<4096, 64, 0, stream>>>(gfd, da_w, da_b, xdec, td);
    GDesc dd1{dh_b, 512, dh2i_t, 512, dh2i_b, xdec + 128, 640, nullptr,
              nullptr, 0, FAR, 512, 1, 4};
    GDesc dd2{dh_b, 512, dec_whh_t, 512, dec_bhh, ghD, 1536, nullptr,
              nullptr, 0, FAR, 512, 0, 12};
    gemm128<<<dim3(12, 32, 2), 256, 0, stream>>>(dd1, dd2);
    GDesc dgi{xdec, 640, dec_wih_t, 640, dec_bih, giD, 1536, nullptr,
              nullptr, 0, FAR, 640, 0, 12};
    gemm128<<<dim3(12, 32, 1), 256, 0, stream>>>(dgi, dgi);
    gru_pw<<<1024, 256, 0, stream>>>(giD, ghD, dh_f, dh_b, 4096);
    regdot<<<1024, 256, 0, stream>>>(dh_b, reg_w, reg_b, out_dec, 1, td);
  }
}

// Round 5
// 1356.010 us; speedup vs baseline: 1.9174x; 1.1237x over previous
//
#include <hip/hip_runtime.h>

// SGNet on MI355X. fp32 in/out, internal bf16 MFMA pipeline, fp32 master GRU
// states. Round-5: decoder attention precomputed for all 12 steps (depends
// only on gfd), A-column-split GEMMs (no xcat/xdec assembly), gru+reghead
// fused, goal_mega absorbs encoder GRU + e2g, single transpose dispatch.

typedef unsigned short u16;
typedef __attribute__((ext_vector_type(8))) short bf16x8;
typedef __attribute__((ext_vector_type(4))) float f32x4;

static __device__ __forceinline__ float b2f(u16 u) {
  union { float f; unsigned int i; } x; x.i = ((unsigned int)u) << 16; return x.f;
}
static __device__ __forceinline__ u16 f2b(float f) {
  unsigned int u = __float_as_uint(f);
  unsigned int r = (u + 0x7FFFu + ((u >> 16) & 1u)) >> 16;
  return (u16)r;
}
static __device__ __forceinline__ float fsig(float x) {
  return __fdividef(1.f, 1.f + __expf(-x));
}
static __device__ __forceinline__ float ftanh(float x) {
  return 1.f - __fdividef(2.f, __expf(2.f * x) + 1.f);
}

// ---------------------------------------------------------------- all transposes, one dispatch
struct TransArgs {
  const float* in[13];
  u16* out[13];
  int K[13], N[13], t0[13], nx[13];
};

__global__ __launch_bounds__(256) void transpose_all(TransArgs ta) {
  int bid = blockIdx.x;
  int i = 0;
  for (int k = 1; k < 13; k++) if (bid >= ta.t0[k]) i = k;
  const float* in = ta.in[i];
  u16* out = ta.out[i];
  int K = ta.K[i], N = ta.N[i];
  int local = bid - ta.t0[i];
  int nx = ta.nx[i];
  int tx = local % nx, ty = local / nx;
  __shared__ u16 tbuf[32][33];
  int n0 = tx * 32, k0 = ty * 32;
  int x = threadIdx.x & 31, y = threadIdx.x >> 5;  // 32 x 8
  for (int q = 0; q < 4; q++) tbuf[y + 8 * q][x] = f2b(in[(size_t)(k0 + y + 8 * q) * N + n0 + x]);
  __syncthreads();
  for (int q = 0; q < 4; q++) out[(size_t)(n0 + y + 8 * q) * K + k0 + x] = tbuf[x][y + 8 * q];
}

// ---------------------------------------------------------------- embed (K=6)
__global__ __launch_bounds__(256) void embed_kernel(const float* __restrict__ inp,
                                                    const float* __restrict__ w,
                                                    const float* __restrict__ bias,
                                                    u16* __restrict__ traj) {
  int t = blockIdx.x * 256 + threadIdx.x;             // 8*512*512
  int h = t & 511, b = (t >> 9) & 511, e = t >> 18;
  float acc = bias[h];
  for (int i = 0; i < 6; i++) acc += inp[(b * 8 + e) * 6 + i] * w[i * 512 + h];
  traj[((e * 512) + b) * 512 + h] = f2b(fmaxf(acc, 0.f));
}

// ---------------------------------------------------------------- 128-tile MFMA GEMM
// Dual-descriptor (blockIdx.z). A column-split: K-cols >= asplit read from A2.
// Output column routing: cols >= route_n go to Cb2.
struct GDesc {
  const u16* A; int lda;
  const u16* A2; int lda2; int asplit;
  const u16* W; int ldw;
  const float* bias;
  u16* Cb; int ldc;
  float* Cf;
  u16* Cb2; int ldc2; int route_n;
  int K; int relu; int nblk;
};

__global__ __launch_bounds__(256) void gemm128(GDesc d0, GDesc d1) {
  GDesc d = (blockIdx.z == 0) ? d0 : d1;
  if ((int)blockIdx.x >= d.nblk) return;
  __shared__ u16 As[128][72];   // 144B row (16B-aligned); 2-way banks (free)
  __shared__ u16 Bs[128][72];
  int tid = threadIdx.x;
  int m0 = blockIdx.y * 128, n0 = blockIdx.x * 128;
  int lane = tid & 63, wave = tid >> 6;
  int wr = wave >> 1, wc = wave & 1;
  int mrow = lane & 15, kq = (lane >> 4) * 8;
  int srow = tid >> 3, scol = (tid & 7) * 8;
  f32x4 acc[4][4] = {};

  for (int k0 = 0; k0 < d.K; k0 += 64) {
    const u16* Asrc; int Alda, kk;
    if (k0 < d.asplit) { Asrc = d.A; Alda = d.lda; kk = k0; }
    else               { Asrc = d.A2; Alda = d.lda2; kk = k0 - d.asplit; }
    __syncthreads();
#pragma unroll
    for (int p = 0; p < 4; p++) {
      int r = srow + p * 32;
      *(uint4*)&As[r][scol] = *(const uint4*)&Asrc[(size_t)(m0 + r) * Alda + kk + scol];
      *(uint4*)&Bs[r][scol] = *(const uint4*)&d.W[(size_t)(n0 + r) * d.ldw + k0 + scol];
    }
    __syncthreads();
#pragma unroll
    for (int ks = 0; ks < 2; ks++) {
      bf16x8 af[4], bf[4];
#pragma unroll
      for (int i = 0; i < 4; i++) {
        af[i] = *(const bf16x8*)&As[wr * 64 + i * 16 + mrow][ks * 32 + kq];
        bf[i] = *(const bf16x8*)&Bs[wc * 64 + i * 16 + mrow][ks * 32 + kq];
      }
#pragma unroll
      for (int i = 0; i < 4; i++)
#pragma unroll
        for (int j = 0; j < 4; j++)
          acc[i][j] = __builtin_amdgcn_mfma_f32_16x16x32_bf16(af[i], bf[j], acc[i][j], 0, 0, 0);
    }
  }
  int col = lane & 15, rq = (lane >> 4) * 4;
#pragma unroll
  for (int j = 0; j < 4; j++) {
    int n = n0 + wc * 64 + j * 16 + col;
    float bv = d.bias ? d.bias[n] : 0.f;
    bool r2 = (n >= d.route_n);
    u16* cb = r2 ? d.Cb2 : d.Cb;
    int ldc = r2 ? d.ldc2 : d.ldc;
    int nn = r2 ? n - d.route_n : n;
#pragma unroll
    for (int i = 0; i < 4; i++)
#pragma unroll
      for (int r = 0; r < 4; r++) {
        int m = m0 + wr * 64 + i * 16 + rq + r;
        float v = acc[i][j][r] + bv;
        if (d.relu) v = fmaxf(v, 0.f);
        cb[(size_t)m * ldc + nn] = f2b(v);
        if (d.Cf) d.Cf[(size_t)m * d.ldc + n] = v;
      }
  }
}

// ---------------------------------------------------------------- decoder GRU + reg head fused
// 4096 rows; one wave per row (64 lanes x 8 elems). Writes dh (fp32+bf16) and out_dec.
__global__ __launch_bounds__(256) void gru_pw_reg(const u16* __restrict__ gi,
                                                  const u16* __restrict__ gh,
                                                  float* __restrict__ hf,
                                                  u16* __restrict__ hb,
                                                  const float* __restrict__ rw,
                                                  const float* __restrict__ rb,
                                                  float* __restrict__ out, int td) {
  int t = blockIdx.x * 256 + threadIdx.x;
  int r = t >> 6, lane = threadIdx.x & 63;
  int j8 = lane * 8;
  size_t base = (size_t)r * 1536 + j8;
  uint4 ir4 = *(const uint4*)&gi[base];
  uint4 iz4 = *(const uint4*)&gi[base + 512];
  uint4 in4 = *(const uint4*)&gi[base + 1024];
  uint4 hr4 = *(const uint4*)&gh[base];
  uint4 hz4 = *(const uint4*)&gh[base + 512];
  uint4 hn4 = *(const uint4*)&gh[base + 1024];
  const u16* irp = (const u16*)&ir4; const u16* izp = (const u16*)&iz4;
  const u16* inp = (const u16*)&in4; const u16* hrp = (const u16*)&hr4;
  const u16* hzp = (const u16*)&hz4; const u16* hnp = (const u16*)&hn4;
  size_t hoff = (size_t)r * 512 + j8;
  float hv[8];
  *(float4*)&hv[0] = *(const float4*)&hf[hoff];
  *(float4*)&hv[4] = *(const float4*)&hf[hoff + 4];
  u16 hbv[8];
  float p0 = 0.f, p1 = 0.f;
  for (int j = 0; j < 8; j++) {
    float rr = fsig(b2f(irp[j]) + b2f(hrp[j]));
    float zz = fsig(b2f(izp[j]) + b2f(hzp[j]));
    float nn = ftanh(b2f(inp[j]) + rr * b2f(hnp[j]));
    float ho = (1.f - zz) * nn + zz * hv[j];
    hv[j] = ho; hbv[j] = f2b(ho);
    p0 += ho * rw[(j8 + j) * 2];
    p1 += ho * rw[(j8 + j) * 2 + 1];
  }
  *(float4*)&hf[hoff] = *(const float4*)&hv[0];
  *(float4*)&hf[hoff + 4] = *(const float4*)&hv[4];
  *(uint4*)&hb[hoff] = *(const uint4*)&hbv[0];
  for (int o = 32; o; o >>= 1) { p0 += __shfl_down(p0, o); p1 += __shfl_down(p1, o); }
  if (lane == 0) {
    int e = r >> 9, b = r & 511;
    size_t off = ((size_t)(b * 8 + e) * 12 + td) * 2;
    out[off] = p0 + rb[0];
    out[off + 1] = p1 + rb[1];
  }
}

// ---------------------------------------------------------------- goal_mega
// Prologue: encoder GRU pointwise (16 rows) + e2g MFMA. Then 12-step goal GRU
// + g2e + encoder attention (into gfe_out). 16 waves/block, 16 rows/block.
__global__ __launch_bounds__(1024) void goal_mega(const u16* __restrict__ gi_g,     // [512,1536]
                                                  const u16* __restrict__ gh_g,     // [512,1536]
                                                  float* __restrict__ teh_f,        // [512,512] fp32 master
                                                  u16* __restrict__ teh_out,        // [512,512] bf16 hist slot
                                                  const u16* __restrict__ e2g_t,    // [128,512]
                                                  const float* __restrict__ e2g_b,  // [128]
                                                  const u16* __restrict__ wih_t,    // [384,128]
                                                  const u16* __restrict__ whh_t,    // [384,128]
                                                  const float* __restrict__ bih,    // [384]
                                                  const float* __restrict__ bhh,    // [384]
                                                  const u16* __restrict__ g2i_t,    // [128,128]
                                                  const float* __restrict__ g2i_b,  // [128]
                                                  const u16* __restrict__ g2e_t,    // [128,128]
                                                  const float* __restrict__ g2e_b,  // [128]
                                                  const float* __restrict__ eaw,    // [128]
                                                  const float* __restrict__ eab,    // [1]
                                                  u16* __restrict__ goals,          // [12,512,128] e-slice
                                                  u16* __restrict__ gfe_out) {      // [512,128]
  __shared__ float ghf[16][128];
  __shared__ u16   ghb[16][136];
  __shared__ u16   gib[16][136];
  __shared__ float gi3[16][388];
  __shared__ float gh3[16][388];
  __shared__ u16   gfe_l[12][16][128];
  __shared__ u16   tehb[16][520];   // stride 1040B = 4-bank shift/row -> 2-way (free)
  int tid = threadIdx.x;
  int r0 = blockIdx.x * 16;
  int lane = tid & 63, wave = tid >> 6;       // 16 waves
  int mrow = lane & 15, kq = (lane >> 4) * 8;
  int rq4 = (lane >> 4) * 4;

  // persistent B-fragments: phase-1 tiles {w, w+16, w+32} of 48
  bf16x8 Bf[3][4];
  float  bias1[3];
  int    n0s[3];
  bool   isIv[3];
#pragma unroll
  for (int i = 0; i < 3; i++) {
    int tt = wave + 16 * i;
    bool iI = tt < 24;
    int n0 = (iI ? tt : tt - 24) * 16;
    isIv[i] = iI; n0s[i] = n0;
    const u16* Wt = iI ? wih_t : whh_t;
#pragma unroll
    for (int ks = 0; ks < 4; ks++)
      Bf[i][ks] = *(const bf16x8*)&Wt[(n0 + mrow) * 128 + ks * 32 + kq];
    bias1[i] = (iI ? bih : bhh)[n0 + mrow];
  }
  // phase-3 fragments: waves 0-7 -> g2i, waves 8-15 -> g2e
  bf16x8 Gf[4];
  float bias3;
  {
    const u16* W3 = (wave < 8) ? g2i_t : g2e_t;
    const float* B3 = (wave < 8) ? g2i_b : g2e_b;
    int n0 = (wave & 7) * 16;
#pragma unroll
    for (int ks = 0; ks < 4; ks++)
      Gf[ks] = *(const bf16x8*)&W3[(n0 + mrow) * 128 + ks * 32 + kq];
    bias3 = B3[n0 + mrow];
  }

  // zero gib
  {
    u16* gz = &gib[0][0];
    for (int idx = tid; idx < 16 * 136; idx += 1024) gz[idx] = 0;
  }

  // prologue GRU: wave per row (row = wave), 8 elems/lane
  {
    int r = wave;
    int j8 = lane * 8;
    int grow = r0 + r;
    size_t base = (size_t)grow * 1536 + j8;
    uint4 ir4 = *(const uint4*)&gi_g[base];
    uint4 iz4 = *(const uint4*)&gi_g[base + 512];
    uint4 in4 = *(const uint4*)&gi_g[base + 1024];
    uint4 hr4 = *(const uint4*)&gh_g[base];
    uint4 hz4 = *(const uint4*)&gh_g[base + 512];
    uint4 hn4 = *(const uint4*)&gh_g[base + 1024];
    const u16* irp = (const u16*)&ir4; const u16* izp = (const u16*)&iz4;
    const u16* inp = (const u16*)&in4; const u16* hrp = (const u16*)&hr4;
    const u16* hzp = (const u16*)&hz4; const u16* hnp = (const u16*)&hn4;
    size_t hoff = (size_t)grow * 512 + j8;
    float hv[8];
    *(float4*)&hv[0] = *(const float4*)&teh_f[hoff];
    *(float4*)&hv[4] = *(const float4*)&teh_f[hoff + 4];
    u16 hbv[8];
    for (int j = 0; j < 8; j++) {
      float rr = fsig(b2f(irp[j]) + b2f(hrp[j]));
      float zz = fsig(b2f(izp[j]) + b2f(hzp[j]));
      float nn = ftanh(b2f(inp[j]) + rr * b2f(hnp[j]));
      float ho = (1.f - zz) * nn + zz * hv[j];
      hv[j] = ho; hbv[j] = f2b(ho);
    }
    *(float4*)&teh_f[hoff] = *(const float4*)&hv[0];
    *(float4*)&teh_f[hoff + 4] = *(const float4*)&hv[4];
    *(uint4*)&teh_out[hoff] = *(const uint4*)&hbv[0];
    *(uint4*)&tehb[r][j8] = *(const uint4*)&hbv[0];
  }
  __syncthreads();

  // e2g: gh0[16][128] = relu(tehb @ e2g_t^T + b), waves 0-7
  if (wave < 8) {
    int n0 = wave * 16;
    f32x4 acc = {};
#pragma unroll
    for (int ks = 0; ks < 16; ks++) {
      bf16x8 a = *(const bf16x8*)&tehb[mrow][ks * 32 + kq];
      bf16x8 b = *(const bf16x8*)&e2g_t[(size_t)(n0 + mrow) * 512 + ks * 32 + kq];
      acc = __builtin_amdgcn_mfma_f32_16x16x32_bf16(a, b, acc, 0, 0, 0);
    }
    int n = n0 + mrow;
    float bv = e2g_b[n];
#pragma unroll
    for (int r = 0; r < 4; r++) {
      float v = fmaxf(acc[r] + bv, 0.f);
      int m = rq4 + r;
      ghf[m][n] = v;
      ghb[m][n] = f2b(v);
    }
  }
  __syncthreads();

  for (int t = 0; t < 12; t++) {
    // phase 1: gi3 = gi@wih+bih ; gh3 = gh@whh+bhh
    bf16x8 agi[4], agh[4];
#pragma unroll
    for (int ks = 0; ks < 4; ks++) {
      agi[ks] = *(const bf16x8*)&gib[mrow][ks * 32 + kq];
      agh[ks] = *(const bf16x8*)&ghb[mrow][ks * 32 + kq];
    }
#pragma unroll
    for (int i = 0; i < 3; i++) {
      f32x4 acc = {};
#pragma unroll
      for (int ks = 0; ks < 4; ks++)
        acc = __builtin_amdgcn_mfma_f32_16x16x32_bf16(isIv[i] ? agi[ks] : agh[ks],
                                                      Bf[i][ks], acc, 0, 0, 0);
      float* G = isIv[i] ? &gi3[0][0] : &gh3[0][0];
      int n = n0s[i] + mrow;
#pragma unroll
      for (int r = 0; r < 4; r++)
        G[(rq4 + r) * 388 + n] = acc[r] + bias1[i];
    }
    __syncthreads();
    // phase 2: pointwise GRU + emit goals[t]
    for (int idx = tid; idx < 2048; idx += 1024) {
      int m = idx >> 7, j = idx & 127;
      float rr = fsig(gi3[m][j] + gh3[m][j]);
      float zz = fsig(gi3[m][128 + j] + gh3[m][128 + j]);
      float nn = ftanh(gi3[m][256 + j] + rr * gh3[m][256 + j]);
      float h = ghf[m][j];
      float ho = (1.f - zz) * nn + zz * h;
      ghf[m][j] = ho;
      u16 hb = f2b(ho);
      ghb[m][j] = hb;
      goals[(t * 512 + r0 + m) * 128 + j] = hb;
    }
    __syncthreads();
    // phase 3: waves 0-7: gib = relu(gh@g2i+b); waves 8-15: gfe_l[t] = relu(gh@g2e+b)
    {
      f32x4 acc = {};
#pragma unroll
      for (int ks = 0; ks < 4; ks++) {
        bf16x8 a = *(const bf16x8*)&ghb[mrow][ks * 32 + kq];
        acc = __builtin_amdgcn_mfma_f32_16x16x32_bf16(a, Gf[ks], acc, 0, 0, 0);
      }
      int n = (wave & 7) * 16 + mrow;
      if (wave < 8) {
#pragma unroll
        for (int r = 0; r < 4; r++)
          gib[rq4 + r][n] = f2b(fmaxf(acc[r] + bias3, 0.f));
      } else {
#pragma unroll
        for (int r = 0; r < 4; r++)
          gfe_l[t][rq4 + r][n] = f2b(fmaxf(acc[r] + bias3, 0.f));
      }
    }
    __syncthreads();
  }

  // encoder attention (wave w -> row w), write gfe carry
  {
    int m = wave;
    float w0 = eaw[lane], w1 = eaw[lane + 64];
    float eb = eab[0];
    float v0[12], v1[12], lg[12];
#pragma unroll
    for (int t = 0; t < 12; t++) {
      float a = b2f(gfe_l[t][m][lane]);
      float c = b2f(gfe_l[t][m][lane + 64]);
      v0[t] = a; v1[t] = c;
      float p = ftanh(a) * w0 + ftanh(c) * w1;
      for (int o = 32; o; o >>= 1) p += __shfl_xor(p, o);
      lg[t] = fmaxf(p + eb, 0.f);
    }
    float mx = lg[0];
#pragma unroll
    for (int t = 1; t < 12; t++) mx = fmaxf(mx, lg[t]);
    float s = 0.f;
#pragma unroll
    for (int t = 0; t < 12; t++) { lg[t] = __expf(lg[t] - mx); s += lg[t]; }
    float inv = __fdividef(1.f, s);
    float c0 = 0.f, c1 = 0.f;
#pragma unroll
    for (int t = 0; t < 12; t++) { c0 += lg[t] * inv * v0[t]; c1 += lg[t] * inv * v1[t]; }
    gfe_out[(r0 + m) * 128 + lane] = f2b(c0);
    gfe_out[(r0 + m) * 128 + lane + 64] = f2b(c1);
  }
}

// ---------------------------------------------------------------- goal reg head (wave per row)
// row = (e*12+t)*512 + b over ghid [49152,512]
__global__ __launch_bounds__(256) void regdot_goal(const u16* __restrict__ X,
                                                   const float* __restrict__ rw,
                                                   const float* __restrict__ rb,
                                                   float* __restrict__ out) {
  int row = (blockIdx.x * 256 + threadIdx.x) >> 6;
  int lane = threadIdx.x & 63;
  int k0 = lane * 8;
  uint4 xv = *(const uint4*)&X[(size_t)row * 512 + k0];
  const u16* xp = (const u16*)&xv;
  float p0 = 0.f, p1 = 0.f;
  for (int j = 0; j < 8; j++) {
    float x = b2f(xp[j]);
    p0 += x * rw[(k0 + j) * 2];
    p1 += x * rw[(k0 + j) * 2 + 1];
  }
  for (int o = 32; o; o >>= 1) { p0 += __shfl_down(p0, o); p1 += __shfl_down(p1, o); }
  if (lane == 0) {
    int s = row >> 9, b = row & 511;
    int e = s / 12, td = s - e * 12;
    size_t off = ((size_t)(b * 8 + e) * 12 + td) * 2;
    out[off] = p0 + rb[0];
    out[off + 1] = p1 + rb[1];
  }
}

// ---------------------------------------------------------------- decoder ctx, ALL td at once
// block per (e,b) row; gfd row cached in LDS; wave w computes td = w, w+4, w+8.
__global__ __launch_bounds__(256) void attn_ctx_all(const u16* __restrict__ gfd,  // [8,12,512,128]
                                                    const float* __restrict__ daw,
                                                    const float* __restrict__ dab,
                                                    u16* __restrict__ xctx) {      // [12,4096,128]
  __shared__ u16 rowbuf[1536];
  int row = blockIdx.x;            // e*512 + b
  int tid = threadIdx.x;
  int e = row >> 9, b = row & 511;
  for (int idx = tid; idx < 1536; idx += 256) {
    int s = idx >> 7, h = idx & 127;
    rowbuf[idx] = gfd[((size_t)(e * 12 + s) * 512 + b) * 128 + h];
  }
  __syncthreads();
  int lane = tid & 63, wave = tid >> 6;
  float w0 = daw[lane], w1 = daw[lane + 64];
  float bias = dab[0];
  float base = fmaxf(bias, 0.f);
  for (int q = 0; q < 3; q++) {
    int td = wave + q * 4;
    float v0[12], v1[12], lg[12];
    for (int s = 0; s < 12; s++) {
      if (s < td) { lg[s] = base; v0[s] = 0.f; v1[s] = 0.f; }
      else {
        float a = b2f(rowbuf[s * 128 + lane]);
        float c = b2f(rowbuf[s * 128 + 64 + lane]);
        v0[s] = a; v1[s] = c;
        float p = ftanh(a) * w0 + ftanh(c) * w1;
        for (int o = 32; o; o >>= 1) p += __shfl_xor(p, o);
        lg[s] = fmaxf(p + bias, 0.f);
      }
    }
    float m = lg[0];
    for (int s = 1; s < 12; s++) m = fmaxf(m, lg[s]);
    float ssum = 0.f;
    for (int s = 0; s < 12; s++) { lg[s] = __expf(lg[s] - m); ssum += lg[s]; }
    float inv = __fdividef(1.f, ssum);
    float c0 = 0.f, c1 = 0.f;
    for (int s = 0; s < 12; s++) { c0 += lg[s] * inv * v0[s]; c1 += lg[s] * inv * v1[s]; }
    size_t o = ((size_t)td * 4096 + row) * 128;
    xctx[o + lane] = f2b(c0);
    xctx[o + lane + 64] = f2b(c1);
  }
}

// ================================================================ host
extern "C" void kernel_launch(void* const* d_in, const int* in_sizes, int n_in,
                              void* d_out, int out_size, void* d_ws, size_t ws_size,
                              hipStream_t stream) {
  const float* inp      = (const float*)d_in[0];
  const float* embed_w  = (const float*)d_in[1];
  const float* embed_b  = (const float*)d_in[2];
  const float* reg_w    = (const float*)d_in[3];
  const float* reg_b    = (const float*)d_in[4];
  const float* ea_w     = (const float*)d_in[5];
  const float* ea_b     = (const float*)d_in[6];
  const float* da_w     = (const float*)d_in[7];
  const float* da_b     = (const float*)d_in[8];
  const float* e2g_w    = (const float*)d_in[9];
  const float* e2g_b    = (const float*)d_in[10];
  const float* e2d_w    = (const float*)d_in[11];
  const float* e2d_b    = (const float*)d_in[12];
  const float* gh2i_w   = (const float*)d_in[13];
  const float* gh2i_b   = (const float*)d_in[14];
  const float* dh2i_w   = (const float*)d_in[15];
  const float* dh2i_b   = (const float*)d_in[16];
  const float* gh2t_w   = (const float*)d_in[17];
  const float* gh2t_b   = (const float*)d_in[18];
  const float* g2e_w    = (const float*)d_in[19];
  const float* g2e_b    = (const float*)d_in[20];
  const float* g2d_w    = (const float*)d_in[21];
  const float* g2d_b    = (const float*)d_in[22];
  const float* enc_wih  = (const float*)d_in[23];
  const float* enc_whh  = (const float*)d_in[24];
  const float* enc_bih  = (const float*)d_in[25];
  const float* enc_bhh  = (const float*)d_in[26];
  const float* goal_wih = (const float*)d_in[27];
  const float* goal_whh = (const float*)d_in[28];
  const float* goal_bih = (const float*)d_in[29];
  const float* goal_bhh = (const float*)d_in[30];
  const float* dec_wih  = (const float*)d_in[31];
  const float* dec_whh  = (const float*)d_in[32];
  const float* dec_bih  = (const float*)d_in[33];
  const float* dec_bhh  = (const float*)d_in[34];

  char* ws = (char*)d_ws;
  size_t off = 0;
  auto alloc = [&](size_t bytes) -> char* {
    char* p = ws + off; off += (bytes + 255) & ~(size_t)255; return p;
  };
  const size_t TSZ = 512 * 512;
  // ---- zero region (contiguous): teh_f, teh_hist, gfe_buf
  float* teh_f    = (float*)alloc(TSZ * 4);
  u16*   teh_hist = (u16*)  alloc(9 * TSZ * 2);
  u16*   gfe_buf  = (u16*)  alloc(512 * 128 * 2);
  size_t zero_bytes = off;
  u16*   traj     = (u16*)  alloc((size_t)8 * TSZ * 2);
  u16*   goals_all= (u16*)  alloc((size_t)8 * 6144 * 128 * 2); // [8][12,512,128]
  u16*   ghid     = (u16*)  alloc((size_t)49152 * 512 * 2);
  u16*   gfd      = (u16*)  alloc((size_t)49152 * 128 * 2);    // [8,12,512,128]
  u16*   xctx     = (u16*)  alloc((size_t)12 * 4096 * 128 * 2);
  float* dh_f     = (float*)alloc((size_t)4096 * 512 * 4);
  u16*   dh_b     = (u16*)  alloc((size_t)4096 * 512 * 2);
  u16*   ddi      = (u16*)  alloc((size_t)4096 * 512 * 2);
  u16*   giD      = (u16*)  alloc((size_t)4096 * 1536 * 2);
  u16*   ghD      = (u16*)  alloc((size_t)4096 * 1536 * 2);
  u16*   giE = giD, *ghE = ghD;                                // enc aliases rows 0:512
  u16* enc_wih_t  = (u16*)alloc((size_t)1536 * 640 * 2);
  u16* enc_whh_t  = (u16*)alloc((size_t)1536 * 512 * 2);
  u16* dec_wih_t  = (u16*)alloc((size_t)1536 * 640 * 2);
  u16* dec_whh_t  = (u16*)alloc((size_t)1536 * 512 * 2);
  u16* e2g_t      = (u16*)alloc(128 * 512 * 2);
  u16* e2d_t      = (u16*)alloc(512 * 512 * 2);
  u16* dh2i_t     = (u16*)alloc(512 * 512 * 2);
  u16* head_t     = (u16*)alloc(640 * 128 * 2);   // rows 0-511: gh2t_t, 512-639: g2d_t
  u16* g2e_t      = (u16*)alloc(128 * 128 * 2);
  u16* goal_wih_t = (u16*)alloc(384 * 128 * 2);
  u16* goal_whh_t = (u16*)alloc(384 * 128 * 2);
  u16* gh2i_t     = (u16*)alloc(128 * 128 * 2);
  float* head_b   = (float*)alloc(640 * 4);
  if (off > ws_size) return;

  float* out_goal = (float*)d_out;
  float* out_dec  = out_goal + (size_t)512 * 8 * 12 * 2;

  hipMemsetAsync(teh_f, 0, zero_bytes, stream);

  // ---- all weight transposes in one dispatch
  TransArgs ta;
  int ntile = 0, ti = 0;
  auto push = [&](const float* in, u16* out, int K, int N) {
    ta.in[ti] = in; ta.out[ti] = out; ta.K[ti] = K; ta.N[ti] = N;
    ta.t0[ti] = ntile; ta.nx[ti] = N / 32;
    ntile += (K / 32) * (N / 32); ti++;
  };
  push(enc_wih, enc_wih_t, 640, 1536);
  push(enc_whh, enc_whh_t, 512, 1536);
  push(dec_wih, dec_wih_t, 640, 1536);
  push(dec_whh, dec_whh_t, 512, 1536);
  push(e2g_w, e2g_t, 512, 128);
  push(e2d_w, e2d_t, 512, 512);
  push(dh2i_w, dh2i_t, 512, 512);
  push(gh2t_w, head_t, 128, 512);
  push(g2d_w, head_t + 512 * 128, 128, 128);
  push(g2e_w, g2e_t, 128, 128);
  push(goal_wih, goal_wih_t, 128, 384);
  push(goal_whh, goal_whh_t, 128, 384);
  push(gh2i_w, gh2i_t, 128, 128);
  transpose_all<<<ntile, 256, 0, stream>>>(ta);
  hipMemcpyAsync(head_b, gh2t_b, 512 * 4, hipMemcpyDeviceToDevice, stream);
  hipMemcpyAsync(head_b + 512, g2d_b, 128 * 4, hipMemcpyDeviceToDevice, stream);

  embed_kernel<<<8192, 256, 0, stream>>>(inp, embed_w, embed_b, traj);

  const int FAR = 1 << 30;

  // ---------------- encoder chain (2 dispatches per step)
  for (int e = 0; e < 8; ++e) {
    GDesc dgi{traj + (size_t)e * TSZ, 512, gfe_buf, 128, 512,
              enc_wih_t, 640, enc_bih, giE, 1536, nullptr,
              nullptr, 0, FAR, 640, 0, 12};
    GDesc dgh{teh_hist + (size_t)e * TSZ, 512, nullptr, 0, FAR,
              enc_whh_t, 512, enc_bhh, ghE, 1536, nullptr,
              nullptr, 0, FAR, 512, 0, 12};
    gemm128<<<dim3(12, 4, 2), 256, 0, stream>>>(dgi, dgh);
    goal_mega<<<32, 1024, 0, stream>>>(giE, ghE, teh_f, teh_hist + (size_t)(e + 1) * TSZ,
                                       e2g_t, e2g_b,
                                       goal_wih_t, goal_whh_t, goal_bih, goal_bhh,
                                       gh2i_t, gh2i_b, g2e_t, g2e_b, ea_w, ea_b,
                                       goals_all + (size_t)e * 6144 * 128, gfe_buf);
  }

  // ---------------- deferred batched encoder sinks
  {
    GDesc de2d{teh_hist + TSZ, 512, nullptr, 0, FAR,
               e2d_t, 512, e2d_b, dh_b, 512, dh_f,
               nullptr, 0, FAR, 512, 1, 4};
    gemm128<<<dim3(4, 32, 1), 256, 0, stream>>>(de2d, de2d);
    GDesc dhead{goals_all, 128, nullptr, 0, FAR,
                head_t, 128, head_b, ghid, 512, nullptr,
                gfd, 128, 512, 128, 1, 5};
    gemm128<<<dim3(5, 384, 1), 256, 0, stream>>>(dhead, dhead);
    regdot_goal<<<12288, 256, 0, stream>>>(ghid, reg_w, reg_b, out_goal);
    attn_ctx_all<<<4096, 256, 0, stream>>>(gfd, da_w, da_b, xctx);
  }

  // ---------------- batched decoder (3 dispatches per step)
  for (int td = 0; td < 12; ++td) {
    GDesc dd1{dh_b, 512, nullptr, 0, FAR,
              dh2i_t, 512, dh2i_b, ddi, 512, nullptr,
              nullptr, 0, FAR, 512, 1, 4};
    GDesc dd2{dh_b, 512, nullptr, 0, FAR,
              dec_whh_t, 512, dec_bhh, ghD, 1536, nullptr,
              nullptr, 0, FAR, 512, 0, 12};
    gemm128<<<dim3(12, 32, 2), 256, 0, stream>>>(dd1, dd2);
    GDesc dgi{xctx + (size_t)td * 4096 * 128, 128, ddi, 512, 128,
              dec_wih_t, 640, dec_bih, giD, 1536, nullptr,
              nullptr, 0, FAR, 640, 0, 12};
    gemm128<<<dim3(12, 32, 1), 256, 0, stream>>>(dgi, dgi);
    gru_pw_reg<<<1024, 256, 0, stream>>>(giD, ghD, dh_f, dh_b, reg_w, reg_b, out_dec, td);
  }
}